// Round 1
// baseline (132.289 us; speedup 1.0000x reference)
//
#include <hip/hip_runtime.h>
#include <type_traits>

// DCNv2 forward, MI355X (gfx950).  v4
//  k_pre:        x NCHW f32 -> xbf NHWC bf16 + weight repack.
//                wmain is now written in MFMA-B-FRAGMENT order so the fused
//                GEMM can consume B directly from global/L2 (no LDS for B):
//                wmain[(k>>5)*8192 + (oc>>4)*512 + ((k>>3)&3)*128 + (oc&15)*8 + (k&7)]
//  k_offconv:    implicit-im2col MFMA GEMM -> om[r][32] f32 (bias+sigmoid).
//                (unchanged; uses wrep, whose layout is unchanged)
//  k_gemm_fused: deformable-im2col fused GEMM. v4: 64x256 output tile,
//                grid 256x1 (NO blockIdx.y split -> the deformable blend is
//                computed exactly once per output row instead of twice).
//                16 waves in a 2x8 grid of 32x32 wave tiles. A (blended
//                values) is the only LDS tenant: 3 x 8 KB triple buffer,
//                ONE lgkm-only barrier per kstep, blend(k) consumes gathers
//                issued at k-2. B fragments are loaded global->VGPR in
//                fragment order (4 x dwordx4 per wave per kstep, L2-resident,
//                depth-1 slotted prefetch) - B LDS writes/reads eliminated.

typedef __bf16 bf16x8 __attribute__((ext_vector_type(8)));
typedef float  f32x4  __attribute__((ext_vector_type(4)));
typedef unsigned short ushort8 __attribute__((ext_vector_type(8)));
typedef unsigned short ushort4v __attribute__((ext_vector_type(4)));
typedef unsigned int   uint2v  __attribute__((ext_vector_type(2)));

#define XBF_OFF   0u            // 4*4096*256*2  = 8,388,608
#define WREP_OFF  8388608u      // 32*2304*2     =   147,456
#define WMAIN_OFF 8536064u      // 256*2304*2    = 1,179,648
#define OM_OFF    9715712u      // 16384*32*4    = 2,097,152

// wait lgkmcnt(0) only (vmcnt=no wait), then barrier.
#define LGKM0_BAR() do { __builtin_amdgcn_s_waitcnt(0xC07F); __builtin_amdgcn_s_barrier(); } while (0)

template <int N> using ic = std::integral_constant<int, N>;

__device__ __forceinline__ unsigned short f2bf(float f) {
  unsigned int u = __float_as_uint(f);
  u += 0x7fffu + ((u >> 16) & 1u);
  return (unsigned short)(u >> 16);
}
__device__ __forceinline__ float bf2f(unsigned short h) {
  return __uint_as_float(((unsigned int)h) << 16);
}

// ---------------- merged transpose + weight repack ----------------
__global__ __launch_bounds__(256) void k_pre(const float* __restrict__ x,
                                             const float* __restrict__ w_off,
                                             const float* __restrict__ dcn_w,
                                             unsigned short* __restrict__ xbf,
                                             unsigned short* __restrict__ wrep,
                                             unsigned short* __restrict__ wmain) {
  __shared__ float tile[32][65];
  __shared__ unsigned short lsh[2304];
  int b = blockIdx.x;
  int t = threadIdx.x;
  if (b < 2048) {               // transpose role
    int n  = b >> 9;
    int cb = (b >> 6) & 7;
    int xb = b & 63;
    int xx  = t & 63;
    int cc0 = t >> 6;
#pragma unroll
    for (int j = 0; j < 8; ++j) {
      int cc = cc0 + j * 4;
      tile[cc][xx] = x[((size_t)(n * 256 + cb * 32 + cc) << 12) + xb * 64 + xx];
    }
    __syncthreads();
    int ccw = t & 31;
    int xw0 = t >> 5;
#pragma unroll
    for (int j = 0; j < 8; ++j) {
      int xw = xw0 + j * 8;
      xbf[((size_t)((n << 12) + xb * 64 + xw)) * 256 + cb * 32 + ccw] = f2bf(tile[ccw][xw]);
    }
  } else {                      // repack role: one block per output channel
    int ocb = b - 2048;
    if (ocb < 32) {             // offset-conv weights: layout unchanged
      int oc = ocb;
      if (oc >= 27) {
#pragma unroll
        for (int j = 0; j < 9; ++j) wrep[oc * 2304 + j * 256 + t] = 0;
        return;
      }
      const float* base = w_off + (size_t)oc * 2304;
#pragma unroll
      for (int j = 0; j < 9; ++j) lsh[j * 256 + t] = f2bf(base[t * 9 + j]);
      __syncthreads();
#pragma unroll
      for (int j = 0; j < 9; ++j) wrep[oc * 2304 + j * 256 + t] = lsh[j * 256 + t];
    } else {                    // main weights: MFMA B-fragment order
      int oc = ocb - 32;
      const float* base = dcn_w + (size_t)oc * 2304;
      int oco = ((oc >> 4) << 9) + (oc & 15) * 8;
#pragma unroll
      for (int j = 0; j < 9; ++j) {
        int k = j * 256 + t;    // logical K index: tap-major, channel-minor
        wmain[((k >> 5) << 13) + oco + (((k >> 3) & 3) << 7) + (k & 7)] =
            f2bf(base[t * 9 + j]);
      }
    }
  }
}

// ---------------- offset-field conv: K-split-4, BK=64, depth-2 prefetch ------
__global__ __launch_bounds__(1024) void k_offconv(const unsigned short* __restrict__ xbf,
                                                  const unsigned short* __restrict__ wrep,
                                                  const float* __restrict__ bias,
                                                  float* __restrict__ om) {
  __shared__ __align__(16) unsigned short SHa[4][64 * 64];
  __shared__ __align__(16) unsigned short SHb[4][32 * 64];
  int t = threadIdx.x;
  int wave = t >> 6, lane = t & 63;
  int grp = wave >> 2, wv = wave & 3;
  int tg = t & 255;
  int bm = ((blockIdx.x & 7) << 5) + (blockIdx.x >> 3);   // XCD swizzle
  int n = bm >> 6, oy = bm & 63;

  unsigned short* As = SHa[grp];
  unsigned short* Bs = SHb[grp];

  int arow = tg >> 2, acc4 = tg & 3;
  int brow = tg >> 3, bch = tg & 7;

  f32x4 acc0 = {0.f, 0.f, 0.f, 0.f};
  f32x4 acc1 = {0.f, 0.f, 0.f, 0.f};

  ushort8 av[2][2]; ushort8 bv[2];
  auto prefetch = [&](int ktg, auto slotc) {
    constexpr int slot = decltype(slotc)::value;
    int kk = ktg >> 2;
    int c0 = (ktg & 3) * 64;
    int dy = kk / 3 - 1, dx = kk % 3 - 1;
    int yy = oy + dy, xxg = arow + dx;
    bool ok = ((unsigned)yy < 64u) && ((unsigned)xxg < 64u);
    const unsigned short* p = xbf + (size_t)(((n * 64 + yy) * 64 + xxg) * 256 + c0 + acc4 * 16);
#pragma unroll
    for (int g = 0; g < 2; ++g)
      av[slot][g] = ok ? *(const ushort8*)(p + g * 8) : (ushort8){0,0,0,0,0,0,0,0};
    bv[slot] = *(const ushort8*)(wrep + (size_t)brow * 2304 + ktg * 64 + bch * 8);
  };

  int k0 = grp * 9;
  prefetch(k0, ic<0>{});
  prefetch(k0 + 1, ic<1>{});
  int mr = lane & 15, q = lane >> 4;

  auto step = [&](int kt, auto slotc) {
    constexpr int slot = decltype(slotc)::value;
    LGKM0_BAR();
#pragma unroll
    for (int g = 0; g < 2; ++g) {
      int ch = (acc4 * 2 + g) ^ (arow & 7);
      *(ushort8*)&As[arow * 64 + ch * 8] = av[slot][g];
    }
    { int ch = bch ^ (brow & 7);
      *(ushort8*)&Bs[brow * 64 + ch * 8] = bv[slot]; }
    if (kt + 2 < 9) prefetch(k0 + kt + 2, slotc);
    LGKM0_BAR();
#pragma unroll
    for (int kh = 0; kh < 2; ++kh) {
      int coff = ((q + kh * 4) ^ (mr & 7)) * 8;
      bf16x8 a  = *(const bf16x8*)&As[(wv * 16 + mr) * 64 + coff];
      bf16x8 b0 = *(const bf16x8*)&Bs[mr * 64 + coff];
      bf16x8 b1 = *(const bf16x8*)&Bs[(16 + mr) * 64 + coff];
      acc0 = __builtin_amdgcn_mfma_f32_16x16x32_bf16(a, b0, acc0, 0, 0, 0);
      acc1 = __builtin_amdgcn_mfma_f32_16x16x32_bf16(a, b1, acc1, 0, 0, 0);
    }
  };
  for (int kp = 0; kp < 4; ++kp) {
    step(2 * kp, ic<0>{});
    step(2 * kp + 1, ic<1>{});
  }
  step(8, ic<0>{});

  float* scratch = (float*)&SHa[0][0];
  __syncthreads();
  if (grp > 0) {
#pragma unroll
    for (int nt = 0; nt < 2; ++nt) {
      f32x4 a = nt ? acc1 : acc0;
#pragma unroll
      for (int rg = 0; rg < 4; ++rg)
        scratch[(grp - 1) * 2048 + (wv * 16 + q * 4 + rg) * 32 + nt * 16 + mr] = a[rg];
    }
  }
  __syncthreads();
  if (grp == 0) {
    int r0 = bm * 64;
#pragma unroll
    for (int nt = 0; nt < 2; ++nt) {
      f32x4 a = nt ? acc1 : acc0;
      int oc = nt * 16 + mr;
      float bvl = (oc < 27) ? bias[oc] : 0.f;
#pragma unroll
      for (int rg = 0; rg < 4; ++rg) {
        int pl = wv * 16 + q * 4 + rg;
        float v = a[rg] + bvl + scratch[pl * 32 + oc] +
                  scratch[2048 + pl * 32 + oc] + scratch[4096 + pl * 32 + oc];
        if (oc >= 18 && oc < 27) v = 1.f / (1.f + __expf(-v));
        om[(r0 + pl) * 32 + oc] = v;
      }
    }
  }
}

// ---------------- fused deformable-im2col GEMM v4 ----------------------------
// 1024 thr, 2x8 wave grid over a 64x256 tile, 4 ch/thread sampling (blend done
// ONCE per output row), A-only triple-buffered LDS, B straight from global in
// fragment order, 1 lgkm barrier per kstep.
__global__ __launch_bounds__(1024) void k_gemm_fused(const unsigned short* __restrict__ xbf,
                                                     const float* __restrict__ om,
                                                     const unsigned short* __restrict__ wB,
                                                     float* __restrict__ out) {
  __shared__ __align__(16) unsigned short Ab[3][64 * 64];   // 24 KB total
  int t = threadIdx.x;
  int wave = t >> 6, lane = t & 63;
  int wm = wave & 1, wn = wave >> 1;
  int bmx = ((blockIdx.x & 7) << 5) + (blockIdx.x >> 3);    // XCD swizzle
  int r0 = bmx * 64;

  int srow = t >> 4;            // 0..63 : output row staged by this thread
  int sch  = (t & 15) * 4;      // 4-channel chunk within the 64-ch kstep
  int r = r0 + srow;
  int n = r >> 12, yx = r & 4095, oy = yx >> 6, ox = yx & 63;
  const unsigned short* xb = xbf + (size_t)n * (4096 * 256);
  const float* omr = om + (size_t)r * 32;
  // swizzled A write offset: chunk (t>>1 & 7) XOR (srow&7), half (t&1)
  int wch = ((((t >> 1) & 7) ^ (srow & 7)) << 3) + (t & 1) * 4;

  int mr = lane & 15, q = lane >> 4;
  const unsigned short* Bb0 = wB + wn * 1024 + lane * 8;    // per-wave frag base

  f32x4 acc[2][2];
#pragma unroll
  for (int mt = 0; mt < 2; ++mt)
#pragma unroll
    for (int nt = 0; nt < 2; ++nt) acc[mt][nt] = (f32x4){0.f, 0.f, 0.f, 0.f};

  float pv_y, pv_x, pv_m;
  float cw1, cw2, cw3, cw4;
  int a1, a2, a3, a4;
  float wbuf[2][4];

  auto loadom = [&](int kk) {
    pv_y = omr[2 * kk]; pv_x = omr[2 * kk + 1]; pv_m = omr[18 + kk];
  };
  auto params = [&](int kk) {        // consumes pv_* (already resident)
    float py = (float)(oy + kk / 3) + pv_y;
    float px = (float)(ox + kk % 3) + pv_x;
    float m = pv_m;
    py = fminf(fmaxf(py, 0.f), 65.f);
    px = fminf(fmaxf(px, 0.f), 65.f);
    float fy = floorf(py), fx = floorf(px);
    float ly = py - fy, lx = px - fx;
    float hy = 1.f - ly, hx = 1.f - lx;
    int iy = (int)fy, ix = (int)fx;
    bool yv0 = (iy >= 1) && (iy <= 64);
    bool yv1 = (iy <= 63);
    bool xv0 = (ix >= 1) && (ix <= 64);
    bool xv1 = (ix <= 63);
    int y0 = min(max(iy - 1, 0), 63);
    int y1 = min(iy, 63);
    int x0 = min(max(ix - 1, 0), 63);
    int x1 = min(ix, 63);
    cw1 = (yv0 && xv0) ? hy * hx * m : 0.f;
    cw2 = (yv0 && xv1) ? hy * lx * m : 0.f;
    cw3 = (yv1 && xv0) ? ly * hx * m : 0.f;
    cw4 = (yv1 && xv1) ? ly * lx * m : 0.f;
    a1 = ((y0 << 6) + x0) * 256;
    a2 = ((y0 << 6) + x1) * 256;
    a3 = ((y1 << 6) + x0) * 256;
    a4 = ((y1 << 6) + x1) * 256;
  };

  ushort4v g1[2], g2[2], g3[2], g4[2];
  bf16x8 bfr[2][4];               // [slot][kh*2+nt] B fragments

  auto issueA = [&](int ktg, auto slotc) {
    constexpr int slot = decltype(slotc)::value;
    wbuf[slot][0] = cw1; wbuf[slot][1] = cw2; wbuf[slot][2] = cw3; wbuf[slot][3] = cw4;
    int c = (ktg & 3) * 64 + sch;
    g1[slot] = *(const ushort4v*)(xb + a1 + c);
    g2[slot] = *(const ushort4v*)(xb + a2 + c);
    g3[slot] = *(const ushort4v*)(xb + a3 + c);
    g4[slot] = *(const ushort4v*)(xb + a4 + c);
  };
  auto issueB = [&](int ktg, auto slotc) {
    constexpr int slot = decltype(slotc)::value;
#pragma unroll
    for (int kh = 0; kh < 2; ++kh)
#pragma unroll
      for (int nt = 0; nt < 2; ++nt)
        bfr[slot][kh * 2 + nt] =
            *(const bf16x8*)(Bb0 + (size_t)(ktg * 2 + kh) * 8192 + nt * 512);
  };

  loadom(0);
  params(0);
  loadom(1);
  issueA(0, ic<0>{});
  issueA(1, ic<1>{});
  issueB(0, ic<0>{});

  auto step = [&](int k, auto slotc, auto bufc) {
    constexpr int slot = decltype(slotc)::value;
    constexpr int buf  = decltype(bufc)::value;
    // W(k): blend + perm-pack (vmcnt waits gathers issued at k-2)
    uint2v rs;
#pragma unroll
    for (int p = 0; p < 2; ++p) {
      float va = wbuf[slot][0] * bf2f(g1[slot][2 * p])     + wbuf[slot][1] * bf2f(g2[slot][2 * p]) +
                 wbuf[slot][2] * bf2f(g3[slot][2 * p])     + wbuf[slot][3] * bf2f(g4[slot][2 * p]);
      float vb = wbuf[slot][0] * bf2f(g1[slot][2 * p + 1]) + wbuf[slot][1] * bf2f(g2[slot][2 * p + 1]) +
                 wbuf[slot][2] * bf2f(g3[slot][2 * p + 1]) + wbuf[slot][3] * bf2f(g4[slot][2 * p + 1]);
      unsigned ua = __float_as_uint(va) + 0x8000u;
      unsigned ub = __float_as_uint(vb) + 0x8000u;
      rs[p] = __builtin_amdgcn_perm(ub, ua, 0x07060302u);
    }
    // S(k): store A into buf (safe: last reader M(k-3) drained 2 bars ago)
    *(uint2v*)&Ab[buf][srow * 64 + wch] = rs;
    // issue gathers for k+2 (slot now free) and B frags for k+1
    if (k + 2 < 36) {
      if (((k + 2) & 3) == 0) {
        int kk = (k + 2) >> 2;
        params(kk);
        loadom(kk < 8 ? kk + 1 : 8);
      }
      issueA(k + 2, slotc);
    }
    if (k + 1 < 36) issueB(k + 1, ic<1 - slot>{});
    LGKM0_BAR();                 // S(k) visible to all; global loads stay in flight
    // M(k)
#pragma unroll
    for (int kh = 0; kh < 2; ++kh) {
      int coff = ((q + kh * 4) ^ (mr & 7)) * 8;
      bf16x8 af0 = *(const bf16x8*)&Ab[buf][(wm * 32 + mr) * 64 + coff];
      bf16x8 af1 = *(const bf16x8*)&Ab[buf][(wm * 32 + 16 + mr) * 64 + coff];
      acc[0][0] = __builtin_amdgcn_mfma_f32_16x16x32_bf16(af0, bfr[slot][kh * 2 + 0], acc[0][0], 0, 0, 0);
      acc[0][1] = __builtin_amdgcn_mfma_f32_16x16x32_bf16(af0, bfr[slot][kh * 2 + 1], acc[0][1], 0, 0, 0);
      acc[1][0] = __builtin_amdgcn_mfma_f32_16x16x32_bf16(af1, bfr[slot][kh * 2 + 0], acc[1][0], 0, 0, 0);
      acc[1][1] = __builtin_amdgcn_mfma_f32_16x16x32_bf16(af1, bfr[slot][kh * 2 + 1], acc[1][1], 0, 0, 0);
    }
  };

  for (int kp = 0; kp < 6; ++kp) {
    int k = kp * 6;
    step(k + 0, ic<0>{}, ic<0>{});
    step(k + 1, ic<1>{}, ic<1>{});
    step(k + 2, ic<0>{}, ic<2>{});
    step(k + 3, ic<1>{}, ic<0>{});
    step(k + 4, ic<0>{}, ic<1>{});
    step(k + 5, ic<1>{}, ic<2>{});
  }

  // epilogue: direct stores
#pragma unroll
  for (int mt = 0; mt < 2; ++mt)
#pragma unroll
    for (int nt = 0; nt < 2; ++nt) {
      int p = r0 + wm * 32 + mt * 16 + q * 4;
      int o = wn * 32 + nt * 16 + mr;
      int nn = p >> 12, pyx = p & 4095;
      *(f32x4*)(out + ((size_t)(nn * 256 + o) << 12) + pyx) = acc[mt][nt];
    }
}

extern "C" void kernel_launch(void* const* d_in, const int* in_sizes, int n_in,
                              void* d_out, int out_size, void* d_ws, size_t ws_size,
                              hipStream_t stream) {
  const float* x     = (const float*)d_in[0];
  const float* w_off = (const float*)d_in[1];
  const float* b_off = (const float*)d_in[2];
  const float* dcn_w = (const float*)d_in[3];
  float* out = (float*)d_out;
  char* ws = (char*)d_ws;
  unsigned short* xbf   = (unsigned short*)(ws + XBF_OFF);
  unsigned short* wrep  = (unsigned short*)(ws + WREP_OFF);
  unsigned short* wmain = (unsigned short*)(ws + WMAIN_OFF);
  float*          om    = (float*)(ws + OM_OFF);

  k_pre<<<2048 + 288, 256, 0, stream>>>(x, w_off, dcn_w, xbf, wrep, wmain);
  k_offconv<<<256, 1024, 0, stream>>>(xbf, wrep, b_off, om);
  k_gemm_fused<<<256, 1024, 0, stream>>>(xbf, om, wmain, out);
}

// Round 2
// 130.901 us; speedup vs baseline: 1.0106x; 1.0106x over previous
//
#include <hip/hip_runtime.h>
#include <type_traits>

// DCNv2 forward, MI355X (gfx950).  v5
//  k_pre:        x NCHW f32 -> xbf NHWC bf16 + weight repack.
//                wmain in MFMA-B-FRAGMENT order:
//                wmain[(k>>5)*8192 + (oc>>4)*512 + ((k>>3)&3)*128 + (oc&15)*8 + (k&7)]
//  k_offconv:    implicit-im2col MFMA GEMM -> om[r][32] f32 (bias+sigmoid).
//  k_gemm_fused: deformable-im2col fused GEMM. v5: 32x256 tile, 512 thr
//                (8 waves, 1x8 wave grid), grid 512 -> 2 blocks/CU so two
//                independent barrier groups overlap each other's stalls
//                (v4 regression post-mortem: 1 block/CU, 16 lockstep waves,
//                M-phase vmcnt wait on depth-1 B prefetch = latency-bound).
//                Blend still computed exactly ONCE per output row.
//                B register prefetch now depth-2 via 3 rotating slots
//                (slot index == k%3 LDS buf index); the MFMA's vmcnt wait
//                has ~2 ksteps of cover. A-gather slots stay depth-2 (x2).

typedef __bf16 bf16x8 __attribute__((ext_vector_type(8)));
typedef float  f32x4  __attribute__((ext_vector_type(4)));
typedef unsigned short ushort8 __attribute__((ext_vector_type(8)));
typedef unsigned short ushort4v __attribute__((ext_vector_type(4)));
typedef unsigned int   uint2v  __attribute__((ext_vector_type(2)));

#define XBF_OFF   0u            // 4*4096*256*2  = 8,388,608
#define WREP_OFF  8388608u      // 32*2304*2     =   147,456
#define WMAIN_OFF 8536064u      // 256*2304*2    = 1,179,648
#define OM_OFF    9715712u      // 16384*32*4    = 2,097,152

// wait lgkmcnt(0) only (vmcnt=no wait), then barrier.
#define LGKM0_BAR() do { __builtin_amdgcn_s_waitcnt(0xC07F); __builtin_amdgcn_s_barrier(); } while (0)

template <int N> using ic = std::integral_constant<int, N>;

__device__ __forceinline__ unsigned short f2bf(float f) {
  unsigned int u = __float_as_uint(f);
  u += 0x7fffu + ((u >> 16) & 1u);
  return (unsigned short)(u >> 16);
}
__device__ __forceinline__ float bf2f(unsigned short h) {
  return __uint_as_float(((unsigned int)h) << 16);
}

// ---------------- merged transpose + weight repack ----------------
__global__ __launch_bounds__(256) void k_pre(const float* __restrict__ x,
                                             const float* __restrict__ w_off,
                                             const float* __restrict__ dcn_w,
                                             unsigned short* __restrict__ xbf,
                                             unsigned short* __restrict__ wrep,
                                             unsigned short* __restrict__ wmain) {
  __shared__ float tile[32][65];
  __shared__ unsigned short lsh[2304];
  int b = blockIdx.x;
  int t = threadIdx.x;
  if (b < 2048) {               // transpose role
    int n  = b >> 9;
    int cb = (b >> 6) & 7;
    int xb = b & 63;
    int xx  = t & 63;
    int cc0 = t >> 6;
#pragma unroll
    for (int j = 0; j < 8; ++j) {
      int cc = cc0 + j * 4;
      tile[cc][xx] = x[((size_t)(n * 256 + cb * 32 + cc) << 12) + xb * 64 + xx];
    }
    __syncthreads();
    int ccw = t & 31;
    int xw0 = t >> 5;
#pragma unroll
    for (int j = 0; j < 8; ++j) {
      int xw = xw0 + j * 8;
      xbf[((size_t)((n << 12) + xb * 64 + xw)) * 256 + cb * 32 + ccw] = f2bf(tile[ccw][xw]);
    }
  } else {                      // repack role: one block per output channel
    int ocb = b - 2048;
    if (ocb < 32) {             // offset-conv weights: layout unchanged
      int oc = ocb;
      if (oc >= 27) {
#pragma unroll
        for (int j = 0; j < 9; ++j) wrep[oc * 2304 + j * 256 + t] = 0;
        return;
      }
      const float* base = w_off + (size_t)oc * 2304;
#pragma unroll
      for (int j = 0; j < 9; ++j) lsh[j * 256 + t] = f2bf(base[t * 9 + j]);
      __syncthreads();
#pragma unroll
      for (int j = 0; j < 9; ++j) wrep[oc * 2304 + j * 256 + t] = lsh[j * 256 + t];
    } else {                    // main weights: MFMA B-fragment order
      int oc = ocb - 32;
      const float* base = dcn_w + (size_t)oc * 2304;
      int oco = ((oc >> 4) << 9) + (oc & 15) * 8;
#pragma unroll
      for (int j = 0; j < 9; ++j) {
        int k = j * 256 + t;    // logical K index: tap-major, channel-minor
        wmain[((k >> 5) << 13) + oco + (((k >> 3) & 3) << 7) + (k & 7)] =
            f2bf(base[t * 9 + j]);
      }
    }
  }
}

// ---------------- offset-field conv: K-split-4, BK=64, depth-2 prefetch ------
__global__ __launch_bounds__(1024) void k_offconv(const unsigned short* __restrict__ xbf,
                                                  const unsigned short* __restrict__ wrep,
                                                  const float* __restrict__ bias,
                                                  float* __restrict__ om) {
  __shared__ __align__(16) unsigned short SHa[4][64 * 64];
  __shared__ __align__(16) unsigned short SHb[4][32 * 64];
  int t = threadIdx.x;
  int wave = t >> 6, lane = t & 63;
  int grp = wave >> 2, wv = wave & 3;
  int tg = t & 255;
  int bm = ((blockIdx.x & 7) << 5) + (blockIdx.x >> 3);   // XCD swizzle
  int n = bm >> 6, oy = bm & 63;

  unsigned short* As = SHa[grp];
  unsigned short* Bs = SHb[grp];

  int arow = tg >> 2, acc4 = tg & 3;
  int brow = tg >> 3, bch = tg & 7;

  f32x4 acc0 = {0.f, 0.f, 0.f, 0.f};
  f32x4 acc1 = {0.f, 0.f, 0.f, 0.f};

  ushort8 av[2][2]; ushort8 bv[2];
  auto prefetch = [&](int ktg, auto slotc) {
    constexpr int slot = decltype(slotc)::value;
    int kk = ktg >> 2;
    int c0 = (ktg & 3) * 64;
    int dy = kk / 3 - 1, dx = kk % 3 - 1;
    int yy = oy + dy, xxg = arow + dx;
    bool ok = ((unsigned)yy < 64u) && ((unsigned)xxg < 64u);
    const unsigned short* p = xbf + (size_t)(((n * 64 + yy) * 64 + xxg) * 256 + c0 + acc4 * 16);
#pragma unroll
    for (int g = 0; g < 2; ++g)
      av[slot][g] = ok ? *(const ushort8*)(p + g * 8) : (ushort8){0,0,0,0,0,0,0,0};
    bv[slot] = *(const ushort8*)(wrep + (size_t)brow * 2304 + ktg * 64 + bch * 8);
  };

  int k0 = grp * 9;
  prefetch(k0, ic<0>{});
  prefetch(k0 + 1, ic<1>{});
  int mr = lane & 15, q = lane >> 4;

  auto step = [&](int kt, auto slotc) {
    constexpr int slot = decltype(slotc)::value;
    LGKM0_BAR();
#pragma unroll
    for (int g = 0; g < 2; ++g) {
      int ch = (acc4 * 2 + g) ^ (arow & 7);
      *(ushort8*)&As[arow * 64 + ch * 8] = av[slot][g];
    }
    { int ch = bch ^ (brow & 7);
      *(ushort8*)&Bs[brow * 64 + ch * 8] = bv[slot]; }
    if (kt + 2 < 9) prefetch(k0 + kt + 2, slotc);
    LGKM0_BAR();
#pragma unroll
    for (int kh = 0; kh < 2; ++kh) {
      int coff = ((q + kh * 4) ^ (mr & 7)) * 8;
      bf16x8 a  = *(const bf16x8*)&As[(wv * 16 + mr) * 64 + coff];
      bf16x8 b0 = *(const bf16x8*)&Bs[mr * 64 + coff];
      bf16x8 b1 = *(const bf16x8*)&Bs[(16 + mr) * 64 + coff];
      acc0 = __builtin_amdgcn_mfma_f32_16x16x32_bf16(a, b0, acc0, 0, 0, 0);
      acc1 = __builtin_amdgcn_mfma_f32_16x16x32_bf16(a, b1, acc1, 0, 0, 0);
    }
  };
  for (int kp = 0; kp < 4; ++kp) {
    step(2 * kp, ic<0>{});
    step(2 * kp + 1, ic<1>{});
  }
  step(8, ic<0>{});

  float* scratch = (float*)&SHa[0][0];
  __syncthreads();
  if (grp > 0) {
#pragma unroll
    for (int nt = 0; nt < 2; ++nt) {
      f32x4 a = nt ? acc1 : acc0;
#pragma unroll
      for (int rg = 0; rg < 4; ++rg)
        scratch[(grp - 1) * 2048 + (wv * 16 + q * 4 + rg) * 32 + nt * 16 + mr] = a[rg];
    }
  }
  __syncthreads();
  if (grp == 0) {
    int r0 = bm * 64;
#pragma unroll
    for (int nt = 0; nt < 2; ++nt) {
      f32x4 a = nt ? acc1 : acc0;
      int oc = nt * 16 + mr;
      float bvl = (oc < 27) ? bias[oc] : 0.f;
#pragma unroll
      for (int rg = 0; rg < 4; ++rg) {
        int pl = wv * 16 + q * 4 + rg;
        float v = a[rg] + bvl + scratch[pl * 32 + oc] +
                  scratch[2048 + pl * 32 + oc] + scratch[4096 + pl * 32 + oc];
        if (oc >= 18 && oc < 27) v = 1.f / (1.f + __expf(-v));
        om[(r0 + pl) * 32 + oc] = v;
      }
    }
  }
}

// ---------------- fused deformable-im2col GEMM v5 ----------------------------
// 512 thr, 1x8 wave grid over a 32x256 tile, grid 512 (2 blocks/CU).
// Blend once per output row; A-only triple-buffered LDS (12 KB); B from
// global in fragment order with depth-2 prefetch via 3 rotating reg slots.
__global__ __launch_bounds__(512, 4) void k_gemm_fused(const unsigned short* __restrict__ xbf,
                                                       const float* __restrict__ om,
                                                       const unsigned short* __restrict__ wB,
                                                       float* __restrict__ out) {
  __shared__ __align__(16) unsigned short Ab[3][32 * 64];   // 12 KB total
  int t = threadIdx.x;
  int wave = t >> 6, lane = t & 63;
  int wn = wave;                                            // 8 oc-tiles of 32
  int bmx = ((blockIdx.x & 7) << 6) + (blockIdx.x >> 3);    // XCD swizzle (512)
  int r0 = bmx * 32;

  int srow = t >> 4;            // 0..31 : output row staged by this thread
  int sch  = (t & 15) * 4;      // 4-channel chunk within the 64-ch kstep
  int r = r0 + srow;
  int n = r >> 12, yx = r & 4095, oy = yx >> 6, ox = yx & 63;
  const unsigned short* xb = xbf + (size_t)n * (4096 * 256);
  const float* omr = om + (size_t)r * 32;
  // swizzled A write offset: chunk (t>>1 & 7) XOR (srow&7), half (t&1)
  int wch = ((((t >> 1) & 7) ^ (srow & 7)) << 3) + (t & 1) * 4;

  int mr = lane & 15, q = lane >> 4;
  const unsigned short* Bb0 = wB + wn * 1024 + lane * 8;    // per-wave frag base

  f32x4 acc[2][2];
#pragma unroll
  for (int mt = 0; mt < 2; ++mt)
#pragma unroll
    for (int nt = 0; nt < 2; ++nt) acc[mt][nt] = (f32x4){0.f, 0.f, 0.f, 0.f};

  float pv_y, pv_x, pv_m;
  float cw1, cw2, cw3, cw4;
  int a1, a2, a3, a4;
  float wbuf[2][4];

  auto loadom = [&](int kk) {
    pv_y = omr[2 * kk]; pv_x = omr[2 * kk + 1]; pv_m = omr[18 + kk];
  };
  auto params = [&](int kk) {        // consumes pv_* (already resident)
    float py = (float)(oy + kk / 3) + pv_y;
    float px = (float)(ox + kk % 3) + pv_x;
    float m = pv_m;
    py = fminf(fmaxf(py, 0.f), 65.f);
    px = fminf(fmaxf(px, 0.f), 65.f);
    float fy = floorf(py), fx = floorf(px);
    float ly = py - fy, lx = px - fx;
    float hy = 1.f - ly, hx = 1.f - lx;
    int iy = (int)fy, ix = (int)fx;
    bool yv0 = (iy >= 1) && (iy <= 64);
    bool yv1 = (iy <= 63);
    bool xv0 = (ix >= 1) && (ix <= 64);
    bool xv1 = (ix <= 63);
    int y0 = min(max(iy - 1, 0), 63);
    int y1 = min(iy, 63);
    int x0 = min(max(ix - 1, 0), 63);
    int x1 = min(ix, 63);
    cw1 = (yv0 && xv0) ? hy * hx * m : 0.f;
    cw2 = (yv0 && xv1) ? hy * lx * m : 0.f;
    cw3 = (yv1 && xv0) ? ly * hx * m : 0.f;
    cw4 = (yv1 && xv1) ? ly * lx * m : 0.f;
    a1 = ((y0 << 6) + x0) * 256;
    a2 = ((y0 << 6) + x1) * 256;
    a3 = ((y1 << 6) + x0) * 256;
    a4 = ((y1 << 6) + x1) * 256;
  };

  ushort4v g1[2], g2[2], g3[2], g4[2];
  bf16x8 bfr[3][4];               // [slot = k%3][kh*2+nt] B fragments

  auto issueA = [&](int ktg, auto slotc) {
    constexpr int slot = decltype(slotc)::value;
    wbuf[slot][0] = cw1; wbuf[slot][1] = cw2; wbuf[slot][2] = cw3; wbuf[slot][3] = cw4;
    int c = (ktg & 3) * 64 + sch;
    g1[slot] = *(const ushort4v*)(xb + a1 + c);
    g2[slot] = *(const ushort4v*)(xb + a2 + c);
    g3[slot] = *(const ushort4v*)(xb + a3 + c);
    g4[slot] = *(const ushort4v*)(xb + a4 + c);
  };
  auto issueB = [&](int ktg, auto slotc) {
    constexpr int slot = decltype(slotc)::value;
#pragma unroll
    for (int kh = 0; kh < 2; ++kh)
#pragma unroll
      for (int nt = 0; nt < 2; ++nt)
        bfr[slot][kh * 2 + nt] =
            *(const bf16x8*)(Bb0 + (size_t)(ktg * 2 + kh) * 8192 + nt * 512);
  };

  loadom(0);
  params(0);
  loadom(1);
  issueA(0, ic<0>{});
  issueA(1, ic<1>{});
  issueB(0, ic<0>{});
  issueB(1, ic<1>{});

  auto step = [&](int k, auto aslotc, auto bufc) {
    constexpr int aslot = decltype(aslotc)::value;
    constexpr int buf   = decltype(bufc)::value;
    // W(k): blend + perm-pack (vmcnt waits gathers issued at k-2)
    uint2v rs;
#pragma unroll
    for (int p = 0; p < 2; ++p) {
      float va = wbuf[aslot][0] * bf2f(g1[aslot][2 * p])     + wbuf[aslot][1] * bf2f(g2[aslot][2 * p]) +
                 wbuf[aslot][2] * bf2f(g3[aslot][2 * p])     + wbuf[aslot][3] * bf2f(g4[aslot][2 * p]);
      float vb = wbuf[aslot][0] * bf2f(g1[aslot][2 * p + 1]) + wbuf[aslot][1] * bf2f(g2[aslot][2 * p + 1]) +
                 wbuf[aslot][2] * bf2f(g3[aslot][2 * p + 1]) + wbuf[aslot][3] * bf2f(g4[aslot][2 * p + 1]);
      unsigned ua = __float_as_uint(va) + 0x8000u;
      unsigned ub = __float_as_uint(vb) + 0x8000u;
      rs[p] = __builtin_amdgcn_perm(ub, ua, 0x07060302u);
    }
    // S(k): store A into buf (safe: last reader M(k-3) drained 2 bars ago)
    *(uint2v*)&Ab[buf][srow * 64 + wch] = rs;
    // issue gathers + B frags for k+2 (A slot freed by W(k); B slot (buf+2)%3
    // is only read by M(k+2), and its previous tenant was consumed at M(k-1))
    if (k + 2 < 36) {
      if (((k + 2) & 3) == 0) {
        int kk = (k + 2) >> 2;
        params(kk);
        loadom(kk < 8 ? kk + 1 : 8);
      }
      issueA(k + 2, aslotc);
      issueB(k + 2, ic<(buf + 2) % 3>{});
    }
    LGKM0_BAR();                 // S(k) visible to all; global loads stay in flight
    // M(k): vmcnt wait reaches back to B(k) issued 2 ksteps ago
#pragma unroll
    for (int kh = 0; kh < 2; ++kh) {
      int coff = ((q + kh * 4) ^ (mr & 7)) * 8;
      bf16x8 af0 = *(const bf16x8*)&Ab[buf][mr * 64 + coff];
      bf16x8 af1 = *(const bf16x8*)&Ab[buf][(16 + mr) * 64 + coff];
      acc[0][0] = __builtin_amdgcn_mfma_f32_16x16x32_bf16(af0, bfr[buf][kh * 2 + 0], acc[0][0], 0, 0, 0);
      acc[0][1] = __builtin_amdgcn_mfma_f32_16x16x32_bf16(af0, bfr[buf][kh * 2 + 1], acc[0][1], 0, 0, 0);
      acc[1][0] = __builtin_amdgcn_mfma_f32_16x16x32_bf16(af1, bfr[buf][kh * 2 + 0], acc[1][0], 0, 0, 0);
      acc[1][1] = __builtin_amdgcn_mfma_f32_16x16x32_bf16(af1, bfr[buf][kh * 2 + 1], acc[1][1], 0, 0, 0);
    }
  };

  for (int kp = 0; kp < 6; ++kp) {
    int k = kp * 6;
    step(k + 0, ic<0>{}, ic<0>{});
    step(k + 1, ic<1>{}, ic<1>{});
    step(k + 2, ic<0>{}, ic<2>{});
    step(k + 3, ic<1>{}, ic<0>{});
    step(k + 4, ic<0>{}, ic<1>{});
    step(k + 5, ic<1>{}, ic<2>{});
  }

  // epilogue: direct stores
#pragma unroll
  for (int mt = 0; mt < 2; ++mt)
#pragma unroll
    for (int nt = 0; nt < 2; ++nt) {
      int p = r0 + mt * 16 + q * 4;
      int o = wn * 32 + nt * 16 + mr;
      int nn = p >> 12, pyx = p & 4095;
      *(f32x4*)(out + ((size_t)(nn * 256 + o) << 12) + pyx) = acc[mt][nt];
    }
}

extern "C" void kernel_launch(void* const* d_in, const int* in_sizes, int n_in,
                              void* d_out, int out_size, void* d_ws, size_t ws_size,
                              hipStream_t stream) {
  const float* x     = (const float*)d_in[0];
  const float* w_off = (const float*)d_in[1];
  const float* b_off = (const float*)d_in[2];
  const float* dcn_w = (const float*)d_in[3];
  float* out = (float*)d_out;
  char* ws = (char*)d_ws;
  unsigned short* xbf   = (unsigned short*)(ws + XBF_OFF);
  unsigned short* wrep  = (unsigned short*)(ws + WREP_OFF);
  unsigned short* wmain = (unsigned short*)(ws + WMAIN_OFF);
  float*          om    = (float*)(ws + OM_OFF);

  k_pre<<<2048 + 288, 256, 0, stream>>>(x, w_off, dcn_w, xbf, wrep, wmain);
  k_offconv<<<256, 1024, 0, stream>>>(xbf, wrep, b_off, om);
  k_gemm_fused<<<512, 512, 0, stream>>>(xbf, om, wmain, out);
}

// Round 4
// 126.813 us; speedup vs baseline: 1.0432x; 1.0322x over previous
//
#include <hip/hip_runtime.h>
#include <type_traits>

// DCNv2 forward, MI355X (gfx950).  v7: role-split lockstep (hang-proof overlap).
//  k_pre:        x NCHW f32 -> xbf NHWC bf16 + coalesced weight repack
//                (round-0 version, plain [oc][2304] wmain layout).
//  k_offconv:    implicit-im2col MFMA GEMM -> om[r][32] f32 (round-0 version).
//  k_gemm_fused: 64x256 tile, 768 thr = 12 waves, 1 block/CU, grid 256.
//                waves 0..3  = consumers: 64 rows x 64 oc each (acc[4][4]),
//                              per phase: 16 ds_read_b128 + 32 MFMA on buf (p-1)&1.
//                waves 4..11 = producers: gather+blend A (ONCE per row) + copy B
//                              into buf p&1; depth-1 reg prefetch for next kstep.
//                ALL waves execute the SAME 37 lgkm-only barriers -> no spin
//                locks (v6 post-mortem: sum-counter protocol unsound + hang),
//                yet blend VALU overlaps MFMA/ds_read in every phase because
//                different waves do them. Double-buffered LDS (A 16KB + B 64KB);
//                producer writes buf p&1 while consumer reads (p-1)&1: disjoint.

typedef __bf16 bf16x8 __attribute__((ext_vector_type(8)));
typedef float  f32x4  __attribute__((ext_vector_type(4)));
typedef unsigned short ushort8 __attribute__((ext_vector_type(8)));
typedef unsigned int   uint4v  __attribute__((ext_vector_type(4)));

#define XBF_OFF   0u            // 4*4096*256*2  = 8,388,608
#define WREP_OFF  8388608u      // 32*2304*2     =   147,456
#define WMAIN_OFF 8536064u      // 256*2304*2    = 1,179,648
#define OM_OFF    9715712u      // 16384*32*4    = 2,097,152

// wait lgkmcnt(0) only (vmcnt=no wait), then barrier.
#define LGKM0_BAR() do { __builtin_amdgcn_s_waitcnt(0xC07F); __builtin_amdgcn_s_barrier(); } while (0)

template <int N> using ic = std::integral_constant<int, N>;

__device__ __forceinline__ unsigned short f2bf(float f) {
  unsigned int u = __float_as_uint(f);
  u += 0x7fffu + ((u >> 16) & 1u);
  return (unsigned short)(u >> 16);
}
__device__ __forceinline__ float bf2f(unsigned short h) {
  return __uint_as_float(((unsigned int)h) << 16);
}

// ---------------- merged transpose + coalesced repack ----------------
__global__ __launch_bounds__(256) void k_pre(const float* __restrict__ x,
                                             const float* __restrict__ w_off,
                                             const float* __restrict__ dcn_w,
                                             unsigned short* __restrict__ xbf,
                                             unsigned short* __restrict__ wrep,
                                             unsigned short* __restrict__ wmain) {
  __shared__ float tile[32][65];
  __shared__ unsigned short lsh[2304];
  int b = blockIdx.x;
  int t = threadIdx.x;
  if (b < 2048) {               // transpose role
    int n  = b >> 9;
    int cb = (b >> 6) & 7;
    int xb = b & 63;
    int xx  = t & 63;
    int cc0 = t >> 6;
#pragma unroll
    for (int j = 0; j < 8; ++j) {
      int cc = cc0 + j * 4;
      tile[cc][xx] = x[((size_t)(n * 256 + cb * 32 + cc) << 12) + xb * 64 + xx];
    }
    __syncthreads();
    int ccw = t & 31;
    int xw0 = t >> 5;
#pragma unroll
    for (int j = 0; j < 8; ++j) {
      int xw = xw0 + j * 8;
      xbf[((size_t)((n << 12) + xb * 64 + xw)) * 256 + cb * 32 + ccw] = f2bf(tile[ccw][xw]);
    }
  } else {                      // repack role: one block per output channel
    int ocb = b - 2048;
    const float* src;
    unsigned short* dst;
    int oc;
    if (ocb < 32) { oc = ocb; src = w_off; dst = wrep; }
    else          { oc = ocb - 32; src = dcn_w; dst = wmain; }
    if (ocb < 32 && oc >= 27) {
#pragma unroll
      for (int j = 0; j < 9; ++j) dst[oc * 2304 + j * 256 + t] = 0;
      return;
    }
    const float* base = src + (size_t)oc * 2304;
#pragma unroll
    for (int j = 0; j < 9; ++j) lsh[j * 256 + t] = f2bf(base[t * 9 + j]);
    __syncthreads();
#pragma unroll
    for (int j = 0; j < 9; ++j) dst[oc * 2304 + j * 256 + t] = lsh[j * 256 + t];
  }
}

// ---------------- offset-field conv: K-split-4, BK=64, depth-2 prefetch ------
__global__ __launch_bounds__(1024) void k_offconv(const unsigned short* __restrict__ xbf,
                                                  const unsigned short* __restrict__ wrep,
                                                  const float* __restrict__ bias,
                                                  float* __restrict__ om) {
  __shared__ __align__(16) unsigned short SHa[4][64 * 64];
  __shared__ __align__(16) unsigned short SHb[4][32 * 64];
  int t = threadIdx.x;
  int wave = t >> 6, lane = t & 63;
  int grp = wave >> 2, wv = wave & 3;
  int tg = t & 255;
  int bm = ((blockIdx.x & 7) << 5) + (blockIdx.x >> 3);   // XCD swizzle
  int n = bm >> 6, oy = bm & 63;

  unsigned short* As = SHa[grp];
  unsigned short* Bs = SHb[grp];

  int arow = tg >> 2, acc4 = tg & 3;
  int brow = tg >> 3, bch = tg & 7;

  f32x4 acc0 = {0.f, 0.f, 0.f, 0.f};
  f32x4 acc1 = {0.f, 0.f, 0.f, 0.f};

  ushort8 av[2][2]; ushort8 bv[2];
  auto prefetch = [&](int ktg, auto slotc) {
    constexpr int slot = decltype(slotc)::value;
    int kk = ktg >> 2;
    int c0 = (ktg & 3) * 64;
    int dy = kk / 3 - 1, dx = kk % 3 - 1;
    int yy = oy + dy, xxg = arow + dx;
    bool ok = ((unsigned)yy < 64u) && ((unsigned)xxg < 64u);
    const unsigned short* p = xbf + (size_t)(((n * 64 + yy) * 64 + xxg) * 256 + c0 + acc4 * 16);
#pragma unroll
    for (int g = 0; g < 2; ++g)
      av[slot][g] = ok ? *(const ushort8*)(p + g * 8) : (ushort8){0,0,0,0,0,0,0,0};
    bv[slot] = *(const ushort8*)(wrep + (size_t)brow * 2304 + ktg * 64 + bch * 8);
  };

  int k0 = grp * 9;
  prefetch(k0, ic<0>{});
  prefetch(k0 + 1, ic<1>{});
  int mr = lane & 15, q = lane >> 4;

  auto step = [&](int kt, auto slotc) {
    constexpr int slot = decltype(slotc)::value;
    LGKM0_BAR();
#pragma unroll
    for (int g = 0; g < 2; ++g) {
      int ch = (acc4 * 2 + g) ^ (arow & 7);
      *(ushort8*)&As[arow * 64 + ch * 8] = av[slot][g];
    }
    { int ch = bch ^ (brow & 7);
      *(ushort8*)&Bs[brow * 64 + ch * 8] = bv[slot]; }
    if (kt + 2 < 9) prefetch(k0 + kt + 2, slotc);
    LGKM0_BAR();
#pragma unroll
    for (int kh = 0; kh < 2; ++kh) {
      int coff = ((q + kh * 4) ^ (mr & 7)) * 8;
      bf16x8 a  = *(const bf16x8*)&As[(wv * 16 + mr) * 64 + coff];
      bf16x8 b0 = *(const bf16x8*)&Bs[mr * 64 + coff];
      bf16x8 b1 = *(const bf16x8*)&Bs[(16 + mr) * 64 + coff];
      acc0 = __builtin_amdgcn_mfma_f32_16x16x32_bf16(a, b0, acc0, 0, 0, 0);
      acc1 = __builtin_amdgcn_mfma_f32_16x16x32_bf16(a, b1, acc1, 0, 0, 0);
    }
  };
  for (int kp = 0; kp < 4; ++kp) {
    step(2 * kp, ic<0>{});
    step(2 * kp + 1, ic<1>{});
  }
  step(8, ic<0>{});

  float* scratch = (float*)&SHa[0][0];
  __syncthreads();
  if (grp > 0) {
#pragma unroll
    for (int nt = 0; nt < 2; ++nt) {
      f32x4 a = nt ? acc1 : acc0;
#pragma unroll
      for (int rg = 0; rg < 4; ++rg)
        scratch[(grp - 1) * 2048 + (wv * 16 + q * 4 + rg) * 32 + nt * 16 + mr] = a[rg];
    }
  }
  __syncthreads();
  if (grp == 0) {
    int r0 = bm * 64;
#pragma unroll
    for (int nt = 0; nt < 2; ++nt) {
      f32x4 a = nt ? acc1 : acc0;
      int oc = nt * 16 + mr;
      float bvl = (oc < 27) ? bias[oc] : 0.f;
#pragma unroll
      for (int rg = 0; rg < 4; ++rg) {
        int pl = wv * 16 + q * 4 + rg;
        float v = a[rg] + bvl + scratch[pl * 32 + oc] +
                  scratch[2048 + pl * 32 + oc] + scratch[4096 + pl * 32 + oc];
        if (oc >= 18 && oc < 27) v = 1.f / (1.f + __expf(-v));
        om[(r0 + pl) * 32 + oc] = v;
      }
    }
  }
}

// ---------------- fused deformable-im2col GEMM v7 ----------------------------
// Role-split lockstep: 768 thr, 12 waves, 37 uniform lgkm-only barriers.
__global__ __launch_bounds__(768, 3) void k_gemm_fused(const unsigned short* __restrict__ xbf,
                                                       const float* __restrict__ om,
                                                       const unsigned short* __restrict__ wB,
                                                       float* __restrict__ out) {
  __shared__ __align__(16) unsigned short Ab[2][64 * 64];    // 16 KB
  __shared__ __align__(16) unsigned short Bb[2][256 * 64];   // 64 KB
  int t = threadIdx.x;
  int wave = t >> 6, lane = t & 63;
  int bmx = ((blockIdx.x & 7) << 5) + (blockIdx.x >> 3);     // XCD swizzle
  int r0 = bmx * 64;

  if (wave < 4) {
    // =================== consumers: waves 0..3, 64 rows x 64 oc each ========
    int wn = wave;
    int mr = lane & 15, q = lane >> 4;
    f32x4 acc[4][4];
#pragma unroll
    for (int mt = 0; mt < 4; ++mt)
#pragma unroll
      for (int nt = 0; nt < 4; ++nt) acc[mt][nt] = (f32x4){0.f, 0.f, 0.f, 0.f};

    for (int p = 0; p < 37; ++p) {
      if (p >= 1) {
        int buf = (p - 1) & 1;
#pragma unroll
        for (int kh = 0; kh < 2; ++kh) {
          int coff = ((q + kh * 4) ^ (mr & 7)) * 8;
          bf16x8 af[4], bfv[4];
#pragma unroll
          for (int mt = 0; mt < 4; ++mt)
            af[mt] = *(const bf16x8*)&Ab[buf][(mt * 16 + mr) * 64 + coff];
#pragma unroll
          for (int nt = 0; nt < 4; ++nt)
            bfv[nt] = *(const bf16x8*)&Bb[buf][(wn * 64 + nt * 16 + mr) * 64 + coff];
#pragma unroll
          for (int mt = 0; mt < 4; ++mt)
#pragma unroll
            for (int nt = 0; nt < 4; ++nt)
              acc[mt][nt] = __builtin_amdgcn_mfma_f32_16x16x32_bf16(af[mt], bfv[nt], acc[mt][nt], 0, 0, 0);
        }
      }
      LGKM0_BAR();   // barrier #p+1 (reads retired via MFMA data-deps)
    }

    // epilogue: direct stores
#pragma unroll
    for (int mt = 0; mt < 4; ++mt)
#pragma unroll
      for (int nt = 0; nt < 4; ++nt) {
        int p = r0 + mt * 16 + q * 4;
        int o = wn * 64 + nt * 16 + mr;
        int nn = p >> 12, pyx = p & 4095;
        *(f32x4*)(out + ((size_t)(nn * 256 + o) << 12) + pyx) = acc[mt][nt];
      }
  } else {
    // =================== producers: waves 4..11 =============================
    int pt = t - 256;                    // 0..511
    // A role: 64 rows x 8 ch-chunks of 8
    int srow = pt >> 3, sch = (pt & 7) * 8;
    int r = r0 + srow;
    int n = r >> 12, yx = r & 4095, oy = yx >> 6, ox = yx & 63;
    const unsigned short* xb = xbf + (size_t)n * (4096 * 256);
    const float* omr = om + (size_t)r * 32;
    int wchA = (((pt & 7) ^ (srow & 7)) << 3);
    // B role: 256 oc rows, 2 threads/row, 4 x 16B chunks each
    int prow = pt >> 1;
    int pc0 = (pt & 1) * 4;
    const unsigned short* Bg = wB + (size_t)prow * 2304 + pc0 * 8;
    int bsw0 = (((pc0 + 0) ^ (prow & 7)) << 3);
    int bsw1 = (((pc0 + 1) ^ (prow & 7)) << 3);
    int bsw2 = (((pc0 + 2) ^ (prow & 7)) << 3);
    int bsw3 = (((pc0 + 3) ^ (prow & 7)) << 3);

    float pv_y, pv_x, pv_m;
    float cw1, cw2, cw3, cw4;
    int a1, a2, a3, a4;
    float wbuf[2][4];
    ushort8 g1[2], g2[2], g3[2], g4[2];
    uint4v bvp[2][4];

    auto loadom = [&](int kk) {
      pv_y = omr[2 * kk]; pv_x = omr[2 * kk + 1]; pv_m = omr[18 + kk];
    };
    auto params = [&](int kk) {
      float py = (float)(oy + kk / 3) + pv_y;
      float px = (float)(ox + kk % 3) + pv_x;
      float m = pv_m;
      py = fminf(fmaxf(py, 0.f), 65.f);
      px = fminf(fmaxf(px, 0.f), 65.f);
      float fy = floorf(py), fx = floorf(px);
      float ly = py - fy, lx = px - fx;
      float hy = 1.f - ly, hx = 1.f - lx;
      int iy = (int)fy, ix = (int)fx;
      bool yv0 = (iy >= 1) && (iy <= 64);
      bool yv1 = (iy <= 63);
      bool xv0 = (ix >= 1) && (ix <= 64);
      bool xv1 = (ix <= 63);
      int y0 = min(max(iy - 1, 0), 63);
      int y1 = min(iy, 63);
      int x0 = min(max(ix - 1, 0), 63);
      int x1 = min(ix, 63);
      cw1 = (yv0 && xv0) ? hy * hx * m : 0.f;
      cw2 = (yv0 && xv1) ? hy * lx * m : 0.f;
      cw3 = (yv1 && xv0) ? ly * hx * m : 0.f;
      cw4 = (yv1 && xv1) ? ly * lx * m : 0.f;
      a1 = ((y0 << 6) + x0) * 256;
      a2 = ((y0 << 6) + x1) * 256;
      a3 = ((y1 << 6) + x0) * 256;
      a4 = ((y1 << 6) + x1) * 256;
    };

    auto issueA = [&](int ktg, auto slotc) {
      constexpr int slot = decltype(slotc)::value;
      wbuf[slot][0] = cw1; wbuf[slot][1] = cw2; wbuf[slot][2] = cw3; wbuf[slot][3] = cw4;
      int c = (ktg & 3) * 64 + sch;
      g1[slot] = *(const ushort8*)(xb + a1 + c);
      g2[slot] = *(const ushort8*)(xb + a2 + c);
      g3[slot] = *(const ushort8*)(xb + a3 + c);
      g4[slot] = *(const ushort8*)(xb + a4 + c);
    };
    auto issueB = [&](int ktg, auto slotc) {
      constexpr int slot = decltype(slotc)::value;
#pragma unroll
      for (int j = 0; j < 4; ++j)
        bvp[slot][j] = *(const uint4v*)(Bg + (size_t)ktg * 64 + j * 8);
    };

    loadom(0);
    params(0);
    loadom(1);
    issueA(0, ic<0>{});
    issueB(0, ic<0>{});

    auto pphase = [&](int p, auto slotc) {    // produce kstep p into buf p&1==slot
      constexpr int slot = decltype(slotc)::value;
      // issue next kstep's loads first (~1 full phase of latency cover)
      if (p + 1 < 36) {
        if (((p + 1) & 3) == 0) {
          int kk = (p + 1) >> 2;
          params(kk);
          loadom(kk < 8 ? kk + 1 : 8);
        }
        issueA(p + 1, ic<1 - slot>{});
        issueB(p + 1, ic<1 - slot>{});
      }
      // blend kstep p (vmcnt waits only this slot's gathers; newer stay in flight)
      uint4v rs;
#pragma unroll
      for (int pp = 0; pp < 4; ++pp) {
        float va = wbuf[slot][0] * bf2f(g1[slot][2 * pp])     + wbuf[slot][1] * bf2f(g2[slot][2 * pp]) +
                   wbuf[slot][2] * bf2f(g3[slot][2 * pp])     + wbuf[slot][3] * bf2f(g4[slot][2 * pp]);
        float vb = wbuf[slot][0] * bf2f(g1[slot][2 * pp + 1]) + wbuf[slot][1] * bf2f(g2[slot][2 * pp + 1]) +
                   wbuf[slot][2] * bf2f(g3[slot][2 * pp + 1]) + wbuf[slot][3] * bf2f(g4[slot][2 * pp + 1]);
        unsigned ua = __float_as_uint(va) + 0x8000u;
        unsigned ub = __float_as_uint(vb) + 0x8000u;
        rs[pp] = __builtin_amdgcn_perm(ub, ua, 0x07060302u);
      }
      *(uint4v*)&Ab[slot][srow * 64 + wchA] = rs;
      *(uint4v*)&Bb[slot][prow * 64 + bsw0] = bvp[slot][0];
      *(uint4v*)&Bb[slot][prow * 64 + bsw1] = bvp[slot][1];
      *(uint4v*)&Bb[slot][prow * 64 + bsw2] = bvp[slot][2];
      *(uint4v*)&Bb[slot][prow * 64 + bsw3] = bvp[slot][3];
      LGKM0_BAR();               // writes visible; consumer enters this buf next phase
    };

    for (int pp = 0; pp < 18; ++pp) {
      pphase(2 * pp, ic<0>{});
      pphase(2 * pp + 1, ic<1>{});
    }
    LGKM0_BAR();                 // 37th barrier (idle phase while consumers eat k=35)
  }
}

extern "C" void kernel_launch(void* const* d_in, const int* in_sizes, int n_in,
                              void* d_out, int out_size, void* d_ws, size_t ws_size,
                              hipStream_t stream) {
  const float* x     = (const float*)d_in[0];
  const float* w_off = (const float*)d_in[1];
  const float* b_off = (const float*)d_in[2];
  const float* dcn_w = (const float*)d_in[3];
  float* out = (float*)d_out;
  char* ws = (char*)d_ws;
  unsigned short* xbf   = (unsigned short*)(ws + XBF_OFF);
  unsigned short* wrep  = (unsigned short*)(ws + WREP_OFF);
  unsigned short* wmain = (unsigned short*)(ws + WMAIN_OFF);
  float*          om    = (float*)(ws + OM_OFF);

  k_pre<<<2048 + 288, 256, 0, stream>>>(x, w_off, dcn_w, xbf, wrep, wmain);
  k_offconv<<<256, 1024, 0, stream>>>(xbf, wrep, b_off, om);
  k_gemm_fused<<<256, 768, 0, stream>>>(xbf, om, wmain, out);
}

// Round 5
// 121.182 us; speedup vs baseline: 1.0917x; 1.0465x over previous
//
#include <hip/hip_runtime.h>
#include <type_traits>

// DCNv2 forward, MI355X (gfx950).  v8: role-split + B-in-consumer-registers.
//  k_pre:        x NCHW f32 -> xbf NHWC bf16 + weight repack. wmain in MFMA
//                B-FRAGMENT order (v4/v5 layout, harness-verified):
//                wmain[(k>>5)*8192 + (oc>>4)*512 + ((k>>3)&3)*128 + (oc&15)*8 + (k&7)]
//  k_offconv:    implicit-im2col MFMA GEMM -> om[r][32] f32 (unchanged).
//  k_gemm_fused: 64x256 tile, 1024 thr = 16 waves, 1 block/CU, grid 256.
//                waves 0..7  = consumers: 64 rows x 32 oc each (acc[4][2]=32
//                              AGPR); B fragments prefetched to REGISTERS
//                              (bfr[2][4]=32 VGPR) from fragment-ordered wmain
//                              (L2-resident), issued 1 full phase before use;
//                              lgkm-only barriers keep them in flight.
//                              -> B's 64 KB/kstep of LDS traffic eliminated
//                              (v7 post-mortem: B was 60% of the LDS floor).
//                waves 8..15 = producers: gather+blend A (ONCE per row) into a
//                              2-buf 16 KB LDS ring; no B work at all.
//                All 16 waves execute the SAME 37 lgkm-only barriers (v6
//                lesson: no custom spin sync). Producer writes Ab[p&1] while
//                consumer reads Ab[(p-1)&1]: disjoint each phase.
//                v4's B-from-global failure mode is avoided because only
//                consumer waves carry the B vmcnt, with ~1 phase of cover,
//                while producer VALU runs concurrently on the same SIMDs.

typedef __bf16 bf16x8 __attribute__((ext_vector_type(8)));
typedef float  f32x4  __attribute__((ext_vector_type(4)));
typedef unsigned short ushort8 __attribute__((ext_vector_type(8)));
typedef unsigned int   uint4v  __attribute__((ext_vector_type(4)));

#define XBF_OFF   0u            // 4*4096*256*2  = 8,388,608
#define WREP_OFF  8388608u      // 32*2304*2     =   147,456
#define WMAIN_OFF 8536064u      // 256*2304*2    = 1,179,648
#define OM_OFF    9715712u      // 16384*32*4    = 2,097,152

// wait lgkmcnt(0) only (vmcnt=no wait), then barrier.
#define LGKM0_BAR() do { __builtin_amdgcn_s_waitcnt(0xC07F); __builtin_amdgcn_s_barrier(); } while (0)

template <int N> using ic = std::integral_constant<int, N>;

__device__ __forceinline__ unsigned short f2bf(float f) {
  unsigned int u = __float_as_uint(f);
  u += 0x7fffu + ((u >> 16) & 1u);
  return (unsigned short)(u >> 16);
}
__device__ __forceinline__ float bf2f(unsigned short h) {
  return __uint_as_float(((unsigned int)h) << 16);
}

// ---------------- merged transpose + weight repack ----------------
__global__ __launch_bounds__(256) void k_pre(const float* __restrict__ x,
                                             const float* __restrict__ w_off,
                                             const float* __restrict__ dcn_w,
                                             unsigned short* __restrict__ xbf,
                                             unsigned short* __restrict__ wrep,
                                             unsigned short* __restrict__ wmain) {
  __shared__ float tile[32][65];
  __shared__ unsigned short lsh[2304];
  int b = blockIdx.x;
  int t = threadIdx.x;
  if (b < 2048) {               // transpose role
    int n  = b >> 9;
    int cb = (b >> 6) & 7;
    int xb = b & 63;
    int xx  = t & 63;
    int cc0 = t >> 6;
#pragma unroll
    for (int j = 0; j < 8; ++j) {
      int cc = cc0 + j * 4;
      tile[cc][xx] = x[((size_t)(n * 256 + cb * 32 + cc) << 12) + xb * 64 + xx];
    }
    __syncthreads();
    int ccw = t & 31;
    int xw0 = t >> 5;
#pragma unroll
    for (int j = 0; j < 8; ++j) {
      int xw = xw0 + j * 8;
      xbf[((size_t)((n << 12) + xb * 64 + xw)) * 256 + cb * 32 + ccw] = f2bf(tile[ccw][xw]);
    }
  } else {                      // repack role: one block per output channel
    int ocb = b - 2048;
    if (ocb < 32) {             // offset-conv weights: layout unchanged
      int oc = ocb;
      if (oc >= 27) {
#pragma unroll
        for (int j = 0; j < 9; ++j) wrep[oc * 2304 + j * 256 + t] = 0;
        return;
      }
      const float* base = w_off + (size_t)oc * 2304;
#pragma unroll
      for (int j = 0; j < 9; ++j) lsh[j * 256 + t] = f2bf(base[t * 9 + j]);
      __syncthreads();
#pragma unroll
      for (int j = 0; j < 9; ++j) wrep[oc * 2304 + j * 256 + t] = lsh[j * 256 + t];
    } else {                    // main weights: MFMA B-fragment order
      int oc = ocb - 32;
      const float* base = dcn_w + (size_t)oc * 2304;
      int oco = ((oc >> 4) << 9) + (oc & 15) * 8;
#pragma unroll
      for (int j = 0; j < 9; ++j) {
        int k = j * 256 + t;    // logical K index: tap-major, channel-minor
        wmain[((k >> 5) << 13) + oco + (((k >> 3) & 3) << 7) + (k & 7)] =
            f2bf(base[t * 9 + j]);
      }
    }
  }
}

// ---------------- offset-field conv: K-split-4, BK=64, depth-2 prefetch ------
__global__ __launch_bounds__(1024) void k_offconv(const unsigned short* __restrict__ xbf,
                                                  const unsigned short* __restrict__ wrep,
                                                  const float* __restrict__ bias,
                                                  float* __restrict__ om) {
  __shared__ __align__(16) unsigned short SHa[4][64 * 64];
  __shared__ __align__(16) unsigned short SHb[4][32 * 64];
  int t = threadIdx.x;
  int wave = t >> 6, lane = t & 63;
  int grp = wave >> 2, wv = wave & 3;
  int tg = t & 255;
  int bm = ((blockIdx.x & 7) << 5) + (blockIdx.x >> 3);   // XCD swizzle
  int n = bm >> 6, oy = bm & 63;

  unsigned short* As = SHa[grp];
  unsigned short* Bs = SHb[grp];

  int arow = tg >> 2, acc4 = tg & 3;
  int brow = tg >> 3, bch = tg & 7;

  f32x4 acc0 = {0.f, 0.f, 0.f, 0.f};
  f32x4 acc1 = {0.f, 0.f, 0.f, 0.f};

  ushort8 av[2][2]; ushort8 bv[2];
  auto prefetch = [&](int ktg, auto slotc) {
    constexpr int slot = decltype(slotc)::value;
    int kk = ktg >> 2;
    int c0 = (ktg & 3) * 64;
    int dy = kk / 3 - 1, dx = kk % 3 - 1;
    int yy = oy + dy, xxg = arow + dx;
    bool ok = ((unsigned)yy < 64u) && ((unsigned)xxg < 64u);
    const unsigned short* p = xbf + (size_t)(((n * 64 + yy) * 64 + xxg) * 256 + c0 + acc4 * 16);
#pragma unroll
    for (int g = 0; g < 2; ++g)
      av[slot][g] = ok ? *(const ushort8*)(p + g * 8) : (ushort8){0,0,0,0,0,0,0,0};
    bv[slot] = *(const ushort8*)(wrep + (size_t)brow * 2304 + ktg * 64 + bch * 8);
  };

  int k0 = grp * 9;
  prefetch(k0, ic<0>{});
  prefetch(k0 + 1, ic<1>{});
  int mr = lane & 15, q = lane >> 4;

  auto step = [&](int kt, auto slotc) {
    constexpr int slot = decltype(slotc)::value;
    LGKM0_BAR();
#pragma unroll
    for (int g = 0; g < 2; ++g) {
      int ch = (acc4 * 2 + g) ^ (arow & 7);
      *(ushort8*)&As[arow * 64 + ch * 8] = av[slot][g];
    }
    { int ch = bch ^ (brow & 7);
      *(ushort8*)&Bs[brow * 64 + ch * 8] = bv[slot]; }
    if (kt + 2 < 9) prefetch(k0 + kt + 2, slotc);
    LGKM0_BAR();
#pragma unroll
    for (int kh = 0; kh < 2; ++kh) {
      int coff = ((q + kh * 4) ^ (mr & 7)) * 8;
      bf16x8 a  = *(const bf16x8*)&As[(wv * 16 + mr) * 64 + coff];
      bf16x8 b0 = *(const bf16x8*)&Bs[mr * 64 + coff];
      bf16x8 b1 = *(const bf16x8*)&Bs[(16 + mr) * 64 + coff];
      acc0 = __builtin_amdgcn_mfma_f32_16x16x32_bf16(a, b0, acc0, 0, 0, 0);
      acc1 = __builtin_amdgcn_mfma_f32_16x16x32_bf16(a, b1, acc1, 0, 0, 0);
    }
  };
  for (int kp = 0; kp < 4; ++kp) {
    step(2 * kp, ic<0>{});
    step(2 * kp + 1, ic<1>{});
  }
  step(8, ic<0>{});

  float* scratch = (float*)&SHa[0][0];
  __syncthreads();
  if (grp > 0) {
#pragma unroll
    for (int nt = 0; nt < 2; ++nt) {
      f32x4 a = nt ? acc1 : acc0;
#pragma unroll
      for (int rg = 0; rg < 4; ++rg)
        scratch[(grp - 1) * 2048 + (wv * 16 + q * 4 + rg) * 32 + nt * 16 + mr] = a[rg];
    }
  }
  __syncthreads();
  if (grp == 0) {
    int r0 = bm * 64;
#pragma unroll
    for (int nt = 0; nt < 2; ++nt) {
      f32x4 a = nt ? acc1 : acc0;
      int oc = nt * 16 + mr;
      float bvl = (oc < 27) ? bias[oc] : 0.f;
#pragma unroll
      for (int rg = 0; rg < 4; ++rg) {
        int pl = wv * 16 + q * 4 + rg;
        float v = a[rg] + bvl + scratch[pl * 32 + oc] +
                  scratch[2048 + pl * 32 + oc] + scratch[4096 + pl * 32 + oc];
        if (oc >= 18 && oc < 27) v = 1.f / (1.f + __expf(-v));
        om[(r0 + pl) * 32 + oc] = v;
      }
    }
  }
}

// ---------------- fused deformable-im2col GEMM v8 ----------------------------
// Role-split lockstep, B in consumer registers. 1024 thr, 16 waves, 37 uniform
// lgkm-only barriers. LDS: A double-buffer only (16 KB).
__global__ __launch_bounds__(1024, 4) void k_gemm_fused(const unsigned short* __restrict__ xbf,
                                                        const float* __restrict__ om,
                                                        const unsigned short* __restrict__ wB,
                                                        float* __restrict__ out) {
  __shared__ __align__(16) unsigned short Ab[2][64 * 64];    // 16 KB
  int t = threadIdx.x;
  int wave = t >> 6, lane = t & 63;
  int bmx = ((blockIdx.x & 7) << 5) + (blockIdx.x >> 3);     // XCD swizzle
  int r0 = bmx * 64;

  if (wave < 8) {
    // ============ consumers: waves 0..7, 64 rows x 32 oc each ===============
    int mr = lane & 15, q = lane >> 4;
    const unsigned short* Bg = wB + wave * 1024 + lane * 8;  // frag base (oc blk)
    f32x4 acc[4][2];
#pragma unroll
    for (int mt = 0; mt < 4; ++mt)
#pragma unroll
      for (int nt = 0; nt < 2; ++nt) acc[mt][nt] = (f32x4){0.f, 0.f, 0.f, 0.f};

    bf16x8 bfr[2][4];            // [slot = p&1][kh*2+nt]

    // citer(p): issue B(p) into slot p&1 (islot), MFMA(p-1) from slot 1-islot
    // and Ab[(p-1)&1] == Ab[1-islot]. All register indices compile-time.
    auto citer = [&](int p, bool do_issue, bool do_mfma, auto islotc) {
      constexpr int islot = decltype(islotc)::value;
      constexpr int mslot = 1 - islot;
      if (do_issue) {
#pragma unroll
        for (int kh = 0; kh < 2; ++kh)
#pragma unroll
          for (int nt = 0; nt < 2; ++nt)
            bfr[islot][kh * 2 + nt] =
                *(const bf16x8*)(Bg + (size_t)(p * 2 + kh) * 8192 + nt * 512);
      }
      if (do_mfma) {
#pragma unroll
        for (int kh = 0; kh < 2; ++kh) {
          int coff = ((q + kh * 4) ^ (mr & 7)) * 8;
          bf16x8 af[4];
#pragma unroll
          for (int mt = 0; mt < 4; ++mt)
            af[mt] = *(const bf16x8*)&Ab[mslot][(mt * 16 + mr) * 64 + coff];
#pragma unroll
          for (int mt = 0; mt < 4; ++mt)
#pragma unroll
            for (int nt = 0; nt < 2; ++nt)
              acc[mt][nt] = __builtin_amdgcn_mfma_f32_16x16x32_bf16(
                  af[mt], bfr[mslot][kh * 2 + nt], acc[mt][nt], 0, 0, 0);
        }
      }
      LGKM0_BAR();               // lgkm-only: B loads stay in flight
    };

    citer(0, true, false, ic<0>{});
    citer(1, true, true,  ic<1>{});
    for (int pp = 1; pp < 18; ++pp) {
      citer(2 * pp,     true, true, ic<0>{});
      citer(2 * pp + 1, true, true, ic<1>{});
    }
    citer(36, false, true, ic<0>{});   // tail: MFMA(35) from slot 1, buf 1

    // epilogue: direct stores
#pragma unroll
    for (int mt = 0; mt < 4; ++mt)
#pragma unroll
      for (int nt = 0; nt < 2; ++nt) {
        int p = r0 + mt * 16 + q * 4;
        int o = wave * 32 + nt * 16 + mr;
        int nn = p >> 12, pyx = p & 4095;
        *(f32x4*)(out + ((size_t)(nn * 256 + o) << 12) + pyx) = acc[mt][nt];
      }
  } else {
    // ============ producers: waves 8..15 (A only) ===========================
    int pt = t - 512;                    // 0..511
    int srow = pt >> 3, sch = (pt & 7) * 8;   // 64 rows x 8 ch-chunks of 8
    int r = r0 + srow;
    int n = r >> 12, yx = r & 4095, oy = yx >> 6, ox = yx & 63;
    const unsigned short* xb = xbf + (size_t)n * (4096 * 256);
    const float* omr = om + (size_t)r * 32;
    int wchA = (((pt & 7) ^ (srow & 7)) << 3);

    float pv_y, pv_x, pv_m;
    float cw1, cw2, cw3, cw4;
    int a1, a2, a3, a4;
    float wbuf[2][4];
    ushort8 g1[2], g2[2], g3[2], g4[2];

    auto loadom = [&](int kk) {
      pv_y = omr[2 * kk]; pv_x = omr[2 * kk + 1]; pv_m = omr[18 + kk];
    };
    auto params = [&](int kk) {
      float py = (float)(oy + kk / 3) + pv_y;
      float px = (float)(ox + kk % 3) + pv_x;
      float m = pv_m;
      py = fminf(fmaxf(py, 0.f), 65.f);
      px = fminf(fmaxf(px, 0.f), 65.f);
      float fy = floorf(py), fx = floorf(px);
      float ly = py - fy, lx = px - fx;
      float hy = 1.f - ly, hx = 1.f - lx;
      int iy = (int)fy, ix = (int)fx;
      bool yv0 = (iy >= 1) && (iy <= 64);
      bool yv1 = (iy <= 63);
      bool xv0 = (ix >= 1) && (ix <= 64);
      bool xv1 = (ix <= 63);
      int y0 = min(max(iy - 1, 0), 63);
      int y1 = min(iy, 63);
      int x0 = min(max(ix - 1, 0), 63);
      int x1 = min(ix, 63);
      cw1 = (yv0 && xv0) ? hy * hx * m : 0.f;
      cw2 = (yv0 && xv1) ? hy * lx * m : 0.f;
      cw3 = (yv1 && xv0) ? ly * hx * m : 0.f;
      cw4 = (yv1 && xv1) ? ly * lx * m : 0.f;
      a1 = ((y0 << 6) + x0) * 256;
      a2 = ((y0 << 6) + x1) * 256;
      a3 = ((y1 << 6) + x0) * 256;
      a4 = ((y1 << 6) + x1) * 256;
    };

    auto issueA = [&](int ktg, auto slotc) {
      constexpr int slot = decltype(slotc)::value;
      wbuf[slot][0] = cw1; wbuf[slot][1] = cw2; wbuf[slot][2] = cw3; wbuf[slot][3] = cw4;
      int c = (ktg & 3) * 64 + sch;
      g1[slot] = *(const ushort8*)(xb + a1 + c);
      g2[slot] = *(const ushort8*)(xb + a2 + c);
      g3[slot] = *(const ushort8*)(xb + a3 + c);
      g4[slot] = *(const ushort8*)(xb + a4 + c);
    };

    loadom(0);
    params(0);
    loadom(1);
    issueA(0, ic<0>{});

    auto pphase = [&](int p, auto slotc) {    // produce kstep p into buf p&1==slot
      constexpr int slot = decltype(slotc)::value;
      // issue next kstep's gathers first (~1 full phase of latency cover)
      if (p + 1 < 36) {
        if (((p + 1) & 3) == 0) {
          int kk = (p + 1) >> 2;
          params(kk);
          loadom(kk < 8 ? kk + 1 : 8);
        }
        issueA(p + 1, ic<1 - slot>{});
      }
      // blend kstep p (vmcnt waits only this slot's gathers; newer stay in flight)
      uint4v rs;
#pragma unroll
      for (int pp = 0; pp < 4; ++pp) {
        float va = wbuf[slot][0] * bf2f(g1[slot][2 * pp])     + wbuf[slot][1] * bf2f(g2[slot][2 * pp]) +
                   wbuf[slot][2] * bf2f(g3[slot][2 * pp])     + wbuf[slot][3] * bf2f(g4[slot][2 * pp]);
        float vb = wbuf[slot][0] * bf2f(g1[slot][2 * pp + 1]) + wbuf[slot][1] * bf2f(g2[slot][2 * pp + 1]) +
                   wbuf[slot][2] * bf2f(g3[slot][2 * pp + 1]) + wbuf[slot][3] * bf2f(g4[slot][2 * pp + 1]);
        unsigned ua = __float_as_uint(va) + 0x8000u;
        unsigned ub = __float_as_uint(vb) + 0x8000u;
        rs[pp] = __builtin_amdgcn_perm(ub, ua, 0x07060302u);
      }
      *(uint4v*)&Ab[slot][srow * 64 + wchA] = rs;
      LGKM0_BAR();               // write visible; consumers enter this buf next phase
    };

    for (int pp = 0; pp < 18; ++pp) {
      pphase(2 * pp, ic<0>{});
      pphase(2 * pp + 1, ic<1>{});
    }
    LGKM0_BAR();                 // 37th barrier (idle while consumers eat k=35)
  }
}

extern "C" void kernel_launch(void* const* d_in, const int* in_sizes, int n_in,
                              void* d_out, int out_size, void* d_ws, size_t ws_size,
                              hipStream_t stream) {
  const float* x     = (const float*)d_in[0];
  const float* w_off = (const float*)d_in[1];
  const float* b_off = (const float*)d_in[2];
  const float* dcn_w = (const float*)d_in[3];
  float* out = (float*)d_out;
  char* ws = (char*)d_ws;
  unsigned short* xbf   = (unsigned short*)(ws + XBF_OFF);
  unsigned short* wrep  = (unsigned short*)(ws + WREP_OFF);
  unsigned short* wmain = (unsigned short*)(ws + WMAIN_OFF);
  float*          om    = (float*)(ws + OM_OFF);

  k_pre<<<2048 + 288, 256, 0, stream>>>(x, w_off, dcn_w, xbf, wrep, wmain);
  k_offconv<<<256, 1024, 0, stream>>>(xbf, wrep, b_off, om);
  k_gemm_fused<<<256, 1024, 0, stream>>>(xbf, om, wmain, out);
}

// Round 6
// 114.858 us; speedup vs baseline: 1.1518x; 1.0551x over previous
//
#include <hip/hip_runtime.h>
#include <type_traits>

// DCNv2 forward, MI355X (gfx950).  v9: role-split + B-in-regs + BK=128 phases.
//  k_pre:        x NCHW f32 -> xbf NHWC bf16 + weight repack. wmain in MFMA
//                B-FRAGMENT order (v8 layout, harness-verified):
//                wmain[(k>>5)*8192 + (oc>>4)*512 + ((k>>3)&3)*128 + (oc&15)*8 + (k&7)]
//  k_offconv:    implicit-im2col MFMA GEMM -> om[r][32] f32 (unchanged).
//  k_gemm_fused: 64x256 tile, 1024 thr = 16 waves, 1 block/CU, grid 256.
//                v8 post-mortem: phase ~2700 cyc vs ~900 cyc of real pipe work
//                -> residue is 37 lockstep-barrier convergence events. v9
//                doubles K per phase (BK=128): 19 barriers instead of 37.
//                waves 0..7  consumers (64r x 32oc, acc[4][2]; B frags from
//                fragment-ordered wmain to registers, bfr[2][4] rotating at
//                64-K sub-step granularity - regs unchanged vs v8);
//                waves 8..15 producers (gather+blend A once per row into
//                Ab[2][64][128], two 64-K halves per phase; g[2][4] slots
//                rotate per sub-step, issue distance now 2 sub-steps).
//                Consumer lags one FULL phase: reads buf (p-1)&1 while
//                producer writes p&1 - disjoint by parity every phase.
//                s_setprio(1) around consumer MFMA clusters (T5: helps when
//                waves have role diversity on a SIMD).

typedef __bf16 bf16x8 __attribute__((ext_vector_type(8)));
typedef float  f32x4  __attribute__((ext_vector_type(4)));
typedef unsigned short ushort8 __attribute__((ext_vector_type(8)));
typedef unsigned int   uint4v  __attribute__((ext_vector_type(4)));

#define XBF_OFF   0u            // 4*4096*256*2  = 8,388,608
#define WREP_OFF  8388608u      // 32*2304*2     =   147,456
#define WMAIN_OFF 8536064u      // 256*2304*2    = 1,179,648
#define OM_OFF    9715712u      // 16384*32*4    = 2,097,152

// wait lgkmcnt(0) only (vmcnt=no wait), then barrier.
#define LGKM0_BAR() do { __builtin_amdgcn_s_waitcnt(0xC07F); __builtin_amdgcn_s_barrier(); } while (0)

template <int N> using ic = std::integral_constant<int, N>;

__device__ __forceinline__ unsigned short f2bf(float f) {
  unsigned int u = __float_as_uint(f);
  u += 0x7fffu + ((u >> 16) & 1u);
  return (unsigned short)(u >> 16);
}
__device__ __forceinline__ float bf2f(unsigned short h) {
  return __uint_as_float(((unsigned int)h) << 16);
}

// ---------------- merged transpose + weight repack ----------------
__global__ __launch_bounds__(256) void k_pre(const float* __restrict__ x,
                                             const float* __restrict__ w_off,
                                             const float* __restrict__ dcn_w,
                                             unsigned short* __restrict__ xbf,
                                             unsigned short* __restrict__ wrep,
                                             unsigned short* __restrict__ wmain) {
  __shared__ float tile[32][65];
  __shared__ unsigned short lsh[2304];
  int b = blockIdx.x;
  int t = threadIdx.x;
  if (b < 2048) {               // transpose role
    int n  = b >> 9;
    int cb = (b >> 6) & 7;
    int xb = b & 63;
    int xx  = t & 63;
    int cc0 = t >> 6;
#pragma unroll
    for (int j = 0; j < 8; ++j) {
      int cc = cc0 + j * 4;
      tile[cc][xx] = x[((size_t)(n * 256 + cb * 32 + cc) << 12) + xb * 64 + xx];
    }
    __syncthreads();
    int ccw = t & 31;
    int xw0 = t >> 5;
#pragma unroll
    for (int j = 0; j < 8; ++j) {
      int xw = xw0 + j * 8;
      xbf[((size_t)((n << 12) + xb * 64 + xw)) * 256 + cb * 32 + ccw] = f2bf(tile[ccw][xw]);
    }
  } else {                      // repack role: one block per output channel
    int ocb = b - 2048;
    if (ocb < 32) {             // offset-conv weights: layout unchanged
      int oc = ocb;
      if (oc >= 27) {
#pragma unroll
        for (int j = 0; j < 9; ++j) wrep[oc * 2304 + j * 256 + t] = 0;
        return;
      }
      const float* base = w_off + (size_t)oc * 2304;
#pragma unroll
      for (int j = 0; j < 9; ++j) lsh[j * 256 + t] = f2bf(base[t * 9 + j]);
      __syncthreads();
#pragma unroll
      for (int j = 0; j < 9; ++j) wrep[oc * 2304 + j * 256 + t] = lsh[j * 256 + t];
    } else {                    // main weights: MFMA B-fragment order
      int oc = ocb - 32;
      const float* base = dcn_w + (size_t)oc * 2304;
      int oco = ((oc >> 4) << 9) + (oc & 15) * 8;
#pragma unroll
      for (int j = 0; j < 9; ++j) {
        int k = j * 256 + t;    // logical K index: tap-major, channel-minor
        wmain[((k >> 5) << 13) + oco + (((k >> 3) & 3) << 7) + (k & 7)] =
            f2bf(base[t * 9 + j]);
      }
    }
  }
}

// ---------------- offset-field conv: K-split-4, BK=64, depth-2 prefetch ------
__global__ __launch_bounds__(1024) void k_offconv(const unsigned short* __restrict__ xbf,
                                                  const unsigned short* __restrict__ wrep,
                                                  const float* __restrict__ bias,
                                                  float* __restrict__ om) {
  __shared__ __align__(16) unsigned short SHa[4][64 * 64];
  __shared__ __align__(16) unsigned short SHb[4][32 * 64];
  int t = threadIdx.x;
  int wave = t >> 6, lane = t & 63;
  int grp = wave >> 2, wv = wave & 3;
  int tg = t & 255;
  int bm = ((blockIdx.x & 7) << 5) + (blockIdx.x >> 3);   // XCD swizzle
  int n = bm >> 6, oy = bm & 63;

  unsigned short* As = SHa[grp];
  unsigned short* Bs = SHb[grp];

  int arow = tg >> 2, acc4 = tg & 3;
  int brow = tg >> 3, bch = tg & 7;

  f32x4 acc0 = {0.f, 0.f, 0.f, 0.f};
  f32x4 acc1 = {0.f, 0.f, 0.f, 0.f};

  ushort8 av[2][2]; ushort8 bv[2];
  auto prefetch = [&](int ktg, auto slotc) {
    constexpr int slot = decltype(slotc)::value;
    int kk = ktg >> 2;
    int c0 = (ktg & 3) * 64;
    int dy = kk / 3 - 1, dx = kk % 3 - 1;
    int yy = oy + dy, xxg = arow + dx;
    bool ok = ((unsigned)yy < 64u) && ((unsigned)xxg < 64u);
    const unsigned short* p = xbf + (size_t)(((n * 64 + yy) * 64 + xxg) * 256 + c0 + acc4 * 16);
#pragma unroll
    for (int g = 0; g < 2; ++g)
      av[slot][g] = ok ? *(const ushort8*)(p + g * 8) : (ushort8){0,0,0,0,0,0,0,0};
    bv[slot] = *(const ushort8*)(wrep + (size_t)brow * 2304 + ktg * 64 + bch * 8);
  };

  int k0 = grp * 9;
  prefetch(k0, ic<0>{});
  prefetch(k0 + 1, ic<1>{});
  int mr = lane & 15, q = lane >> 4;

  auto step = [&](int kt, auto slotc) {
    constexpr int slot = decltype(slotc)::value;
    LGKM0_BAR();
#pragma unroll
    for (int g = 0; g < 2; ++g) {
      int ch = (acc4 * 2 + g) ^ (arow & 7);
      *(ushort8*)&As[arow * 64 + ch * 8] = av[slot][g];
    }
    { int ch = bch ^ (brow & 7);
      *(ushort8*)&Bs[brow * 64 + ch * 8] = bv[slot]; }
    if (kt + 2 < 9) prefetch(k0 + kt + 2, slotc);
    LGKM0_BAR();
#pragma unroll
    for (int kh = 0; kh < 2; ++kh) {
      int coff = ((q + kh * 4) ^ (mr & 7)) * 8;
      bf16x8 a  = *(const bf16x8*)&As[(wv * 16 + mr) * 64 + coff];
      bf16x8 b0 = *(const bf16x8*)&Bs[mr * 64 + coff];
      bf16x8 b1 = *(const bf16x8*)&Bs[(16 + mr) * 64 + coff];
      acc0 = __builtin_amdgcn_mfma_f32_16x16x32_bf16(a, b0, acc0, 0, 0, 0);
      acc1 = __builtin_amdgcn_mfma_f32_16x16x32_bf16(a, b1, acc1, 0, 0, 0);
    }
  };
  for (int kp = 0; kp < 4; ++kp) {
    step(2 * kp, ic<0>{});
    step(2 * kp + 1, ic<1>{});
  }
  step(8, ic<0>{});

  float* scratch = (float*)&SHa[0][0];
  __syncthreads();
  if (grp > 0) {
#pragma unroll
    for (int nt = 0; nt < 2; ++nt) {
      f32x4 a = nt ? acc1 : acc0;
#pragma unroll
      for (int rg = 0; rg < 4; ++rg)
        scratch[(grp - 1) * 2048 + (wv * 16 + q * 4 + rg) * 32 + nt * 16 + mr] = a[rg];
    }
  }
  __syncthreads();
  if (grp == 0) {
    int r0 = bm * 64;
#pragma unroll
    for (int nt = 0; nt < 2; ++nt) {
      f32x4 a = nt ? acc1 : acc0;
      int oc = nt * 16 + mr;
      float bvl = (oc < 27) ? bias[oc] : 0.f;
#pragma unroll
      for (int rg = 0; rg < 4; ++rg) {
        int pl = wv * 16 + q * 4 + rg;
        float v = a[rg] + bvl + scratch[pl * 32 + oc] +
                  scratch[2048 + pl * 32 + oc] + scratch[4096 + pl * 32 + oc];
        if (oc >= 18 && oc < 27) v = 1.f / (1.f + __expf(-v));
        om[(r0 + pl) * 32 + oc] = v;
      }
    }
  }
}

// ---------------- fused deformable-im2col GEMM v9 ----------------------------
// Role-split lockstep, B in consumer registers, BK=128 phases (19 barriers).
// 1024 thr, 16 waves, LDS: Ab[2][64*128] = 32 KB.
__global__ __launch_bounds__(1024, 4) void k_gemm_fused(const unsigned short* __restrict__ xbf,
                                                        const float* __restrict__ om,
                                                        const unsigned short* __restrict__ wB,
                                                        float* __restrict__ out) {
  __shared__ __align__(16) unsigned short Ab[2][64 * 128];   // 32 KB
  int t = threadIdx.x;
  int wave = t >> 6, lane = t & 63;
  int bmx = ((blockIdx.x & 7) << 5) + (blockIdx.x >> 3);     // XCD swizzle
  int r0 = bmx * 64;

  if (wave < 8) {
    // ============ consumers: waves 0..7, 64 rows x 32 oc each ===============
    int mr = lane & 15, q = lane >> 4;
    const unsigned short* Bg = wB + wave * 1024 + lane * 8;  // frag base (oc blk)
    f32x4 acc[4][2];
#pragma unroll
    for (int mt = 0; mt < 4; ++mt)
#pragma unroll
      for (int nt = 0; nt < 2; ++nt) acc[mt][nt] = (f32x4){0.f, 0.f, 0.f, 0.f};

    bf16x8 bfr[2][4];            // [slot = ks&1][kh*2+nt], ks = 64-K sub-step

    auto issueB = [&](int ks, auto slotc) {      // B(ks) -> slot
      constexpr int slot = decltype(slotc)::value;
#pragma unroll
      for (int kh = 0; kh < 2; ++kh)
#pragma unroll
        for (int nt = 0; nt < 2; ++nt)
          bfr[slot][kh * 2 + nt] =
              *(const bf16x8*)(Bg + (size_t)(ks * 2 + kh) * 8192 + nt * 512);
    };
    // MFMA for sub-step ks: half = ks&1 (compile-time), B slot = ks&1, buf = (ks>>1)&1
    auto mfma64 = [&](auto halfc, auto bufc) {
      constexpr int half = decltype(halfc)::value;
      constexpr int buf  = decltype(bufc)::value;
      __builtin_amdgcn_s_setprio(1);
#pragma unroll
      for (int kh = 0; kh < 2; ++kh) {
        int coff = half * 64 + ((q + kh * 4) ^ (mr & 7)) * 8;
        bf16x8 af[4];
#pragma unroll
        for (int mt = 0; mt < 4; ++mt)
          af[mt] = *(const bf16x8*)&Ab[buf][(mt * 16 + mr) * 128 + coff];
#pragma unroll
        for (int mt = 0; mt < 4; ++mt)
#pragma unroll
          for (int nt = 0; nt < 2; ++nt)
            acc[mt][nt] = __builtin_amdgcn_mfma_f32_16x16x32_bf16(
                af[mt], bfr[half][kh * 2 + nt], acc[mt][nt], 0, 0, 0);
      }
      __builtin_amdgcn_s_setprio(0);
    };

    // prologue: phase 0 (producers fill buf0); issue B(0).
    issueB(0, ic<0>{});
    LGKM0_BAR();
    // phases p = 1..18: consume buf (p-1)&1 (sub-steps 2p-2, 2p-1)
    auto cphase = [&](int p, auto bufc) {
      issueB(2 * p - 1, ic<1>{});            // used this phase, 2nd sub
      mfma64(ic<0>{}, bufc);                 // MFMA(2p-2): half0, slot0
      if (2 * p < 36) issueB(2 * p, ic<0>{}); // for next phase's 1st sub
      mfma64(ic<1>{}, bufc);                 // MFMA(2p-1): half1, slot1
      LGKM0_BAR();                           // lgkm-only: B loads stay in flight
    };
    for (int pp = 0; pp < 9; ++pp) {
      cphase(2 * pp + 1, ic<0>{});
      cphase(2 * pp + 2, ic<1>{});
    }

    // epilogue: direct stores
#pragma unroll
    for (int mt = 0; mt < 4; ++mt)
#pragma unroll
      for (int nt = 0; nt < 2; ++nt) {
        int p = r0 + mt * 16 + q * 4;
        int o = wave * 32 + nt * 16 + mr;
        int nn = p >> 12, pyx = p & 4095;
        *(f32x4*)(out + ((size_t)(nn * 256 + o) << 12) + pyx) = acc[mt][nt];
      }
  } else {
    // ============ producers: waves 8..15 (A only) ===========================
    int pt = t - 512;                    // 0..511
    int srow = pt >> 3, sch = (pt & 7) * 8;   // 64 rows x 8 ch-chunks of 8
    int r = r0 + srow;
    int n = r >> 12, yx = r & 4095, oy = yx >> 6, ox = yx & 63;
    const unsigned short* xb = xbf + (size_t)n * (4096 * 256);
    const float* omr = om + (size_t)r * 32;
    int wchA = (((pt & 7) ^ (srow & 7)) << 3);

    float pv_y, pv_x, pv_m;
    float cw1, cw2, cw3, cw4;
    int a1, a2, a3, a4;
    float wbuf[2][4];
    ushort8 g1[2], g2[2], g3[2], g4[2];

    auto loadom = [&](int kk) {
      pv_y = omr[2 * kk]; pv_x = omr[2 * kk + 1]; pv_m = omr[18 + kk];
    };
    auto params = [&](int kk) {
      float py = (float)(oy + kk / 3) + pv_y;
      float px = (float)(ox + kk % 3) + pv_x;
      float m = pv_m;
      py = fminf(fmaxf(py, 0.f), 65.f);
      px = fminf(fmaxf(px, 0.f), 65.f);
      float fy = floorf(py), fx = floorf(px);
      float ly = py - fy, lx = px - fx;
      float hy = 1.f - ly, hx = 1.f - lx;
      int iy = (int)fy, ix = (int)fx;
      bool yv0 = (iy >= 1) && (iy <= 64);
      bool yv1 = (iy <= 63);
      bool xv0 = (ix >= 1) && (ix <= 64);
      bool xv1 = (ix <= 63);
      int y0 = min(max(iy - 1, 0), 63);
      int y1 = min(iy, 63);
      int x0 = min(max(ix - 1, 0), 63);
      int x1 = min(ix, 63);
      cw1 = (yv0 && xv0) ? hy * hx * m : 0.f;
      cw2 = (yv0 && xv1) ? hy * lx * m : 0.f;
      cw3 = (yv1 && xv0) ? ly * hx * m : 0.f;
      cw4 = (yv1 && xv1) ? ly * lx * m : 0.f;
      a1 = ((y0 << 6) + x0) * 256;
      a2 = ((y0 << 6) + x1) * 256;
      a3 = ((y1 << 6) + x0) * 256;
      a4 = ((y1 << 6) + x1) * 256;
    };

    auto issueA = [&](int ktg, auto slotc) {
      constexpr int slot = decltype(slotc)::value;
      wbuf[slot][0] = cw1; wbuf[slot][1] = cw2; wbuf[slot][2] = cw3; wbuf[slot][3] = cw4;
      int c = (ktg & 3) * 64 + sch;
      g1[slot] = *(const ushort8*)(xb + a1 + c);
      g2[slot] = *(const ushort8*)(xb + a2 + c);
      g3[slot] = *(const ushort8*)(xb + a3 + c);
      g4[slot] = *(const ushort8*)(xb + a4 + c);
    };
    // blend sub-step from slot, write half of buf
    auto blend = [&](auto slotc, auto halfc, auto bufc) {
      constexpr int slot = decltype(slotc)::value;
      constexpr int half = decltype(halfc)::value;
      constexpr int buf  = decltype(bufc)::value;
      uint4v rs;
#pragma unroll
      for (int pp = 0; pp < 4; ++pp) {
        float va = wbuf[slot][0] * bf2f(g1[slot][2 * pp])     + wbuf[slot][1] * bf2f(g2[slot][2 * pp]) +
                   wbuf[slot][2] * bf2f(g3[slot][2 * pp])     + wbuf[slot][3] * bf2f(g4[slot][2 * pp]);
        float vb = wbuf[slot][0] * bf2f(g1[slot][2 * pp + 1]) + wbuf[slot][1] * bf2f(g2[slot][2 * pp + 1]) +
                   wbuf[slot][2] * bf2f(g3[slot][2 * pp + 1]) + wbuf[slot][3] * bf2f(g4[slot][2 * pp + 1]);
        unsigned ua = __float_as_uint(va) + 0x8000u;
        unsigned ub = __float_as_uint(vb) + 0x8000u;
        rs[pp] = __builtin_amdgcn_perm(ub, ua, 0x07060302u);
      }
      *(uint4v*)&Ab[buf][srow * 128 + half * 64 + wchA] = rs;
    };

    // prologue: gathers for sub-steps 0 and 1 (same tap, quarters 0/1)
    loadom(0);
    params(0);
    loadom(1);
    issueA(0, ic<0>{});
    issueA(1, ic<1>{});

    // pphase(p), p = 0..17: write both halves of buf p&1; prefetch ks = 2p+2, 2p+3
    auto pphase = [&](int p, auto bufc) {
      blend(ic<0>{}, ic<0>{}, bufc);              // ks = 2p  -> half 0
      {
        int ksn = 2 * p + 2;
        if (ksn < 36) {
          if ((ksn & 3) == 0) {
            int kk = ksn >> 2;
            params(kk);
            loadom(kk < 8 ? kk + 1 : 8);
          }
          issueA(ksn, ic<0>{});
        }
      }
      blend(ic<1>{}, ic<1>{}, bufc);              // ks = 2p+1 -> half 1
      {
        int ksn = 2 * p + 3;                      // never ≡0 mod 4: no params
        if (ksn < 36) issueA(ksn, ic<1>{});
      }
      LGKM0_BAR();
    };
    for (int pp = 0; pp < 9; ++pp) {
      pphase(2 * pp,     ic<0>{});
      pphase(2 * pp + 1, ic<1>{});
    }
    LGKM0_BAR();                 // 19th barrier (idle while consumers eat phase 17)
  }
}

extern "C" void kernel_launch(void* const* d_in, const int* in_sizes, int n_in,
                              void* d_out, int out_size, void* d_ws, size_t ws_size,
                              hipStream_t stream) {
  const float* x     = (const float*)d_in[0];
  const float* w_off = (const float*)d_in[1];
  const float* b_off = (const float*)d_in[2];
  const float* dcn_w = (const float*)d_in[3];
  float* out = (float*)d_out;
  char* ws = (char*)d_ws;
  unsigned short* xbf   = (unsigned short*)(ws + XBF_OFF);
  unsigned short* wrep  = (unsigned short*)(ws + WREP_OFF);
  unsigned short* wmain = (unsigned short*)(ws + WMAIN_OFF);
  float*          om    = (float*)(ws + OM_OFF);

  k_pre<<<2048 + 288, 256, 0, stream>>>(x, w_off, dcn_w, xbf, wrep, wmain);
  k_offconv<<<256, 1024, 0, stream>>>(xbf, wrep, b_off, om);
  k_gemm_fused<<<256, 1024, 0, stream>>>(xbf, om, wmain, out);
}

// Round 8
// 113.968 us; speedup vs baseline: 1.1608x; 1.0078x over previous
//
#include <hip/hip_runtime.h>
#include <type_traits>

// DCNv2 forward, MI355X (gfx950).  v11 = bisect of v10's correctness failure.
//  v10 changed TWO things at once and failed absmax (9.8e-2 vs 3.8e-2).
//  v11 keeps ONLY the offconv single-barrier double-buffer (simple parity
//  proof) and restores the gemm to the round-6 HARNESS-VERIFIED v9 version
//  (BK=128, 19 barriers, per-sub-step wbuf[slot] weights) VERBATIM.
//  Pass -> gemm-BK256 rewrite convicted. Fail -> offconv change convicted.
//  k_pre unchanged. wmain stays in MFMA B-fragment order:
//  wmain[(k>>5)*8192 + (oc>>4)*512 + ((k>>3)&3)*128 + (oc&15)*8 + (k&7)]

typedef __bf16 bf16x8 __attribute__((ext_vector_type(8)));
typedef float  f32x4  __attribute__((ext_vector_type(4)));
typedef unsigned short ushort8 __attribute__((ext_vector_type(8)));
typedef unsigned int   uint4v  __attribute__((ext_vector_type(4)));

#define XBF_OFF   0u            // 4*4096*256*2  = 8,388,608
#define WREP_OFF  8388608u      // 32*2304*2     =   147,456
#define WMAIN_OFF 8536064u      // 256*2304*2    = 1,179,648
#define OM_OFF    9715712u      // 16384*32*4    = 2,097,152

// wait lgkmcnt(0) only (vmcnt=no wait), then barrier.
#define LGKM0_BAR() do { __builtin_amdgcn_s_waitcnt(0xC07F); __builtin_amdgcn_s_barrier(); } while (0)

template <int N> using ic = std::integral_constant<int, N>;

__device__ __forceinline__ unsigned short f2bf(float f) {
  unsigned int u = __float_as_uint(f);
  u += 0x7fffu + ((u >> 16) & 1u);
  return (unsigned short)(u >> 16);
}
__device__ __forceinline__ float bf2f(unsigned short h) {
  return __uint_as_float(((unsigned int)h) << 16);
}

// ---------------- merged transpose + weight repack ----------------
__global__ __launch_bounds__(256) void k_pre(const float* __restrict__ x,
                                             const float* __restrict__ w_off,
                                             const float* __restrict__ dcn_w,
                                             unsigned short* __restrict__ xbf,
                                             unsigned short* __restrict__ wrep,
                                             unsigned short* __restrict__ wmain) {
  __shared__ float tile[32][65];
  __shared__ unsigned short lsh[2304];
  int b = blockIdx.x;
  int t = threadIdx.x;
  if (b < 2048) {               // transpose role
    int n  = b >> 9;
    int cb = (b >> 6) & 7;
    int xb = b & 63;
    int xx  = t & 63;
    int cc0 = t >> 6;
#pragma unroll
    for (int j = 0; j < 8; ++j) {
      int cc = cc0 + j * 4;
      tile[cc][xx] = x[((size_t)(n * 256 + cb * 32 + cc) << 12) + xb * 64 + xx];
    }
    __syncthreads();
    int ccw = t & 31;
    int xw0 = t >> 5;
#pragma unroll
    for (int j = 0; j < 8; ++j) {
      int xw = xw0 + j * 8;
      xbf[((size_t)((n << 12) + xb * 64 + xw)) * 256 + cb * 32 + ccw] = f2bf(tile[ccw][xw]);
    }
  } else {                      // repack role: one block per output channel
    int ocb = b - 2048;
    if (ocb < 32) {             // offset-conv weights: layout unchanged
      int oc = ocb;
      if (oc >= 27) {
#pragma unroll
        for (int j = 0; j < 9; ++j) wrep[oc * 2304 + j * 256 + t] = 0;
        return;
      }
      const float* base = w_off + (size_t)oc * 2304;
#pragma unroll
      for (int j = 0; j < 9; ++j) lsh[j * 256 + t] = f2bf(base[t * 9 + j]);
      __syncthreads();
#pragma unroll
      for (int j = 0; j < 9; ++j) wrep[oc * 2304 + j * 256 + t] = lsh[j * 256 + t];
    } else {                    // main weights: MFMA B-fragment order
      int oc = ocb - 32;
      const float* base = dcn_w + (size_t)oc * 2304;
      int oco = ((oc >> 4) << 9) + (oc & 15) * 8;
#pragma unroll
      for (int j = 0; j < 9; ++j) {
        int k = j * 256 + t;    // logical K index: tap-major, channel-minor
        wmain[((k >> 5) << 13) + oco + (((k >> 3) & 3) << 7) + (k & 7)] =
            f2bf(base[t * 9 + j]);
      }
    }
  }
}

// ---------------- offset-field conv: K-split-4, double-buffered, 1 bar/step --
__global__ __launch_bounds__(1024) void k_offconv(const unsigned short* __restrict__ xbf,
                                                  const unsigned short* __restrict__ wrep,
                                                  const float* __restrict__ bias,
                                                  float* __restrict__ om) {
  __shared__ __align__(16) unsigned short SHa[4][2][64 * 64];   // 64 KB
  __shared__ __align__(16) unsigned short SHb[4][2][32 * 64];   // 32 KB
  int t = threadIdx.x;
  int wave = t >> 6, lane = t & 63;
  int grp = wave >> 2, wv = wave & 3;
  int tg = t & 255;
  int bm = ((blockIdx.x & 7) << 5) + (blockIdx.x >> 3);   // XCD swizzle
  int n = bm >> 6, oy = bm & 63;

  unsigned short (*As)[64 * 64] = SHa[grp];
  unsigned short (*Bs)[32 * 64] = SHb[grp];

  int arow = tg >> 2, acc4 = tg & 3;
  int brow = tg >> 3, bch = tg & 7;

  f32x4 acc0 = {0.f, 0.f, 0.f, 0.f};
  f32x4 acc1 = {0.f, 0.f, 0.f, 0.f};

  ushort8 av[2][2]; ushort8 bv[2];
  auto prefetch = [&](int ktg, auto slotc) {
    constexpr int slot = decltype(slotc)::value;
    int kk = ktg >> 2;
    int c0 = (ktg & 3) * 64;
    int dy = kk / 3 - 1, dx = kk % 3 - 1;
    int yy = oy + dy, xxg = arow + dx;
    bool ok = ((unsigned)yy < 64u) && ((unsigned)xxg < 64u);
    const unsigned short* p = xbf + (size_t)(((n * 64 + yy) * 64 + xxg) * 256 + c0 + acc4 * 16);
#pragma unroll
    for (int g = 0; g < 2; ++g)
      av[slot][g] = ok ? *(const ushort8*)(p + g * 8) : (ushort8){0,0,0,0,0,0,0,0};
    bv[slot] = *(const ushort8*)(wrep + (size_t)brow * 2304 + ktg * 64 + bch * 8);
  };

  int k0 = grp * 9;
  prefetch(k0, ic<0>{});
  prefetch(k0 + 1, ic<1>{});
  int mr = lane & 15, q = lane >> 4;

  // step kt: write LDS buf kt&1, prefetch kt+2, ONE barrier, MFMA from buf kt&1.
  // Reads of buf kt&1 by step kt-2 retired (lgkmcnt(0) before barrier kt-1);
  // these writes are after barrier kt-1 in program order -> safe.
  auto step = [&](int kt, auto slotc) {
    constexpr int slot = decltype(slotc)::value;
#pragma unroll
    for (int g = 0; g < 2; ++g) {
      int ch = (acc4 * 2 + g) ^ (arow & 7);
      *(ushort8*)&As[slot][arow * 64 + ch * 8] = av[slot][g];
    }
    { int ch = bch ^ (brow & 7);
      *(ushort8*)&Bs[slot][brow * 64 + ch * 8] = bv[slot]; }
    if (kt + 2 < 9) prefetch(k0 + kt + 2, slotc);
    LGKM0_BAR();
#pragma unroll
    for (int kh = 0; kh < 2; ++kh) {
      int coff = ((q + kh * 4) ^ (mr & 7)) * 8;
      bf16x8 a  = *(const bf16x8*)&As[slot][(wv * 16 + mr) * 64 + coff];
      bf16x8 b0 = *(const bf16x8*)&Bs[slot][mr * 64 + coff];
      bf16x8 b1 = *(const bf16x8*)&Bs[slot][(16 + mr) * 64 + coff];
      acc0 = __builtin_amdgcn_mfma_f32_16x16x32_bf16(a, b0, acc0, 0, 0, 0);
      acc1 = __builtin_amdgcn_mfma_f32_16x16x32_bf16(a, b1, acc1, 0, 0, 0);
    }
  };
  for (int kp = 0; kp < 4; ++kp) {
    step(2 * kp, ic<0>{});
    step(2 * kp + 1, ic<1>{});
  }
  step(8, ic<0>{});

  float* scratch = (float*)&SHa[0][0][0];
  __syncthreads();
  if (grp > 0) {
#pragma unroll
    for (int nt = 0; nt < 2; ++nt) {
      f32x4 a = nt ? acc1 : acc0;
#pragma unroll
      for (int rg = 0; rg < 4; ++rg)
        scratch[(grp - 1) * 2048 + (wv * 16 + q * 4 + rg) * 32 + nt * 16 + mr] = a[rg];
    }
  }
  __syncthreads();
  if (grp == 0) {
    int r0 = bm * 64;
#pragma unroll
    for (int nt = 0; nt < 2; ++nt) {
      f32x4 a = nt ? acc1 : acc0;
      int oc = nt * 16 + mr;
      float bvl = (oc < 27) ? bias[oc] : 0.f;
#pragma unroll
      for (int rg = 0; rg < 4; ++rg) {
        int pl = wv * 16 + q * 4 + rg;
        float v = a[rg] + bvl + scratch[pl * 32 + oc] +
                  scratch[2048 + pl * 32 + oc] + scratch[4096 + pl * 32 + oc];
        if (oc >= 18 && oc < 27) v = 1.f / (1.f + __expf(-v));
        om[(r0 + pl) * 32 + oc] = v;
      }
    }
  }
}

// ---------------- fused deformable-im2col GEMM (v9 VERBATIM, verified) -------
// Role-split lockstep, B in consumer registers, BK=128 phases (19 barriers).
// 1024 thr, 16 waves, LDS: Ab[2][64*128] = 32 KB.
__global__ __launch_bounds__(1024, 4) void k_gemm_fused(const unsigned short* __restrict__ xbf,
                                                        const float* __restrict__ om,
                                                        const unsigned short* __restrict__ wB,
                                                        float* __restrict__ out) {
  __shared__ __align__(16) unsigned short Ab[2][64 * 128];   // 32 KB
  int t = threadIdx.x;
  int wave = t >> 6, lane = t & 63;
  int bmx = ((blockIdx.x & 7) << 5) + (blockIdx.x >> 3);     // XCD swizzle
  int r0 = bmx * 64;

  if (wave < 8) {
    // ============ consumers: waves 0..7, 64 rows x 32 oc each ===============
    int mr = lane & 15, q = lane >> 4;
    const unsigned short* Bg = wB + wave * 1024 + lane * 8;  // frag base (oc blk)
    f32x4 acc[4][2];
#pragma unroll
    for (int mt = 0; mt < 4; ++mt)
#pragma unroll
      for (int nt = 0; nt < 2; ++nt) acc[mt][nt] = (f32x4){0.f, 0.f, 0.f, 0.f};

    bf16x8 bfr[2][4];            // [slot = ks&1][kh*2+nt], ks = 64-K sub-step

    auto issueB = [&](int ks, auto slotc) {      // B(ks) -> slot
      constexpr int slot = decltype(slotc)::value;
#pragma unroll
      for (int kh = 0; kh < 2; ++kh)
#pragma unroll
        for (int nt = 0; nt < 2; ++nt)
          bfr[slot][kh * 2 + nt] =
              *(const bf16x8*)(Bg + (size_t)(ks * 2 + kh) * 8192 + nt * 512);
    };
    // MFMA for sub-step ks: half = ks&1 (compile-time), B slot = ks&1, buf = (ks>>1)&1
    auto mfma64 = [&](auto halfc, auto bufc) {
      constexpr int half = decltype(halfc)::value;
      constexpr int buf  = decltype(bufc)::value;
      __builtin_amdgcn_s_setprio(1);
#pragma unroll
      for (int kh = 0; kh < 2; ++kh) {
        int coff = half * 64 + ((q + kh * 4) ^ (mr & 7)) * 8;
        bf16x8 af[4];
#pragma unroll
        for (int mt = 0; mt < 4; ++mt)
          af[mt] = *(const bf16x8*)&Ab[buf][(mt * 16 + mr) * 128 + coff];
#pragma unroll
        for (int mt = 0; mt < 4; ++mt)
#pragma unroll
          for (int nt = 0; nt < 2; ++nt)
            acc[mt][nt] = __builtin_amdgcn_mfma_f32_16x16x32_bf16(
                af[mt], bfr[half][kh * 2 + nt], acc[mt][nt], 0, 0, 0);
      }
      __builtin_amdgcn_s_setprio(0);
    };

    // prologue: phase 0 (producers fill buf0); issue B(0).
    issueB(0, ic<0>{});
    LGKM0_BAR();
    // phases p = 1..18: consume buf (p-1)&1 (sub-steps 2p-2, 2p-1)
    auto cphase = [&](int p, auto bufc) {
      issueB(2 * p - 1, ic<1>{});            // used this phase, 2nd sub
      mfma64(ic<0>{}, bufc);                 // MFMA(2p-2): half0, slot0
      if (2 * p < 36) issueB(2 * p, ic<0>{}); // for next phase's 1st sub
      mfma64(ic<1>{}, bufc);                 // MFMA(2p-1): half1, slot1
      LGKM0_BAR();                           // lgkm-only: B loads stay in flight
    };
    for (int pp = 0; pp < 9; ++pp) {
      cphase(2 * pp + 1, ic<0>{});
      cphase(2 * pp + 2, ic<1>{});
    }

    // epilogue: direct stores
#pragma unroll
    for (int mt = 0; mt < 4; ++mt)
#pragma unroll
      for (int nt = 0; nt < 2; ++nt) {
        int p = r0 + mt * 16 + q * 4;
        int o = wave * 32 + nt * 16 + mr;
        int nn = p >> 12, pyx = p & 4095;
        *(f32x4*)(out + ((size_t)(nn * 256 + o) << 12) + pyx) = acc[mt][nt];
      }
  } else {
    // ============ producers: waves 8..15 (A only) ===========================
    int pt = t - 512;                    // 0..511
    int srow = pt >> 3, sch = (pt & 7) * 8;   // 64 rows x 8 ch-chunks of 8
    int r = r0 + srow;
    int n = r >> 12, yx = r & 4095, oy = yx >> 6, ox = yx & 63;
    const unsigned short* xb = xbf + (size_t)n * (4096 * 256);
    const float* omr = om + (size_t)r * 32;
    int wchA = (((pt & 7) ^ (srow & 7)) << 3);

    float pv_y, pv_x, pv_m;
    float cw1, cw2, cw3, cw4;
    int a1, a2, a3, a4;
    float wbuf[2][4];
    ushort8 g1[2], g2[2], g3[2], g4[2];

    auto loadom = [&](int kk) {
      pv_y = omr[2 * kk]; pv_x = omr[2 * kk + 1]; pv_m = omr[18 + kk];
    };
    auto params = [&](int kk) {
      float py = (float)(oy + kk / 3) + pv_y;
      float px = (float)(ox + kk % 3) + pv_x;
      float m = pv_m;
      py = fminf(fmaxf(py, 0.f), 65.f);
      px = fminf(fmaxf(px, 0.f), 65.f);
      float fy = floorf(py), fx = floorf(px);
      float ly = py - fy, lx = px - fx;
      float hy = 1.f - ly, hx = 1.f - lx;
      int iy = (int)fy, ix = (int)fx;
      bool yv0 = (iy >= 1) && (iy <= 64);
      bool yv1 = (iy <= 63);
      bool xv0 = (ix >= 1) && (ix <= 64);
      bool xv1 = (ix <= 63);
      int y0 = min(max(iy - 1, 0), 63);
      int y1 = min(iy, 63);
      int x0 = min(max(ix - 1, 0), 63);
      int x1 = min(ix, 63);
      cw1 = (yv0 && xv0) ? hy * hx * m : 0.f;
      cw2 = (yv0 && xv1) ? hy * lx * m : 0.f;
      cw3 = (yv1 && xv0) ? ly * hx * m : 0.f;
      cw4 = (yv1 && xv1) ? ly * lx * m : 0.f;
      a1 = ((y0 << 6) + x0) * 256;
      a2 = ((y0 << 6) + x1) * 256;
      a3 = ((y1 << 6) + x0) * 256;
      a4 = ((y1 << 6) + x1) * 256;
    };

    auto issueA = [&](int ktg, auto slotc) {
      constexpr int slot = decltype(slotc)::value;
      wbuf[slot][0] = cw1; wbuf[slot][1] = cw2; wbuf[slot][2] = cw3; wbuf[slot][3] = cw4;
      int c = (ktg & 3) * 64 + sch;
      g1[slot] = *(const ushort8*)(xb + a1 + c);
      g2[slot] = *(const ushort8*)(xb + a2 + c);
      g3[slot] = *(const ushort8*)(xb + a3 + c);
      g4[slot] = *(const ushort8*)(xb + a4 + c);
    };
    // blend sub-step from slot, write half of buf
    auto blend = [&](auto slotc, auto halfc, auto bufc) {
      constexpr int slot = decltype(slotc)::value;
      constexpr int half = decltype(halfc)::value;
      constexpr int buf  = decltype(bufc)::value;
      uint4v rs;
#pragma unroll
      for (int pp = 0; pp < 4; ++pp) {
        float va = wbuf[slot][0] * bf2f(g1[slot][2 * pp])     + wbuf[slot][1] * bf2f(g2[slot][2 * pp]) +
                   wbuf[slot][2] * bf2f(g3[slot][2 * pp])     + wbuf[slot][3] * bf2f(g4[slot][2 * pp]);
        float vb = wbuf[slot][0] * bf2f(g1[slot][2 * pp + 1]) + wbuf[slot][1] * bf2f(g2[slot][2 * pp + 1]) +
                   wbuf[slot][2] * bf2f(g3[slot][2 * pp + 1]) + wbuf[slot][3] * bf2f(g4[slot][2 * pp + 1]);
        unsigned ua = __float_as_uint(va) + 0x8000u;
        unsigned ub = __float_as_uint(vb) + 0x8000u;
        rs[pp] = __builtin_amdgcn_perm(ub, ua, 0x07060302u);
      }
      *(uint4v*)&Ab[buf][srow * 128 + half * 64 + wchA] = rs;
    };

    // prologue: gathers for sub-steps 0 and 1 (same tap, quarters 0/1)
    loadom(0);
    params(0);
    loadom(1);
    issueA(0, ic<0>{});
    issueA(1, ic<1>{});

    // pphase(p), p = 0..17: write both halves of buf p&1; prefetch ks = 2p+2, 2p+3
    auto pphase = [&](int p, auto bufc) {
      blend(ic<0>{}, ic<0>{}, bufc);              // ks = 2p  -> half 0
      {
        int ksn = 2 * p + 2;
        if (ksn < 36) {
          if ((ksn & 3) == 0) {
            int kk = ksn >> 2;
            params(kk);
            loadom(kk < 8 ? kk + 1 : 8);
          }
          issueA(ksn, ic<0>{});
        }
      }
      blend(ic<1>{}, ic<1>{}, bufc);              // ks = 2p+1 -> half 1
      {
        int ksn = 2 * p + 3;                      // never ≡0 mod 4: no params
        if (ksn < 36) issueA(ksn, ic<1>{});
      }
      LGKM0_BAR();
    };
    for (int pp = 0; pp < 9; ++pp) {
      pphase(2 * pp,     ic<0>{});
      pphase(2 * pp + 1, ic<1>{});
    }
    LGKM0_BAR();                 // 19th barrier (idle while consumers eat phase 17)
  }
}

extern "C" void kernel_launch(void* const* d_in, const int* in_sizes, int n_in,
                              void* d_out, int out_size, void* d_ws, size_t ws_size,
                              hipStream_t stream) {
  const float* x     = (const float*)d_in[0];
  const float* w_off = (const float*)d_in[1];
  const float* b_off = (const float*)d_in[2];
  const float* dcn_w = (const float*)d_in[3];
  float* out = (float*)d_out;
  char* ws = (char*)d_ws;
  unsigned short* xbf   = (unsigned short*)(ws + XBF_OFF);
  unsigned short* wrep  = (unsigned short*)(ws + WREP_OFF);
  unsigned short* wmain = (unsigned short*)(ws + WMAIN_OFF);
  float*          om    = (float*)(ws + OM_OFF);

  k_pre<<<2048 + 288, 256, 0, stream>>>(x, w_off, dcn_w, xbf, wrep, wmain);
  k_offconv<<<256, 1024, 0, stream>>>(xbf, wrep, b_off, om);
  k_gemm_fused<<<256, 1024, 0, stream>>>(xbf, om, wmain, out);
}